// Round 13
// baseline (323.697 us; speedup 1.0000x reference)
//
#include <hip/hip_runtime.h>
#include <hip/hip_bf16.h>

// Problem: B=16, C=64, H=256, W=256, P=2
// y = haar2d_inv( sum_p softthr( (haar2d(x)*v_p) @ w_p^T, tau_p ) ) + x
// Residual folded in wavelet domain: y = invHaar2d(acc + Haar2d(x)).
//
// ws: bf16 (b,c,wref,h) slab (128 MiB) + bf16 weights + packed/permuted v,tau.
//   k_prep : conv_w->bf16; v,tau -> bf16x2 packed, [w][h_inplace] layout
//   k_fwdW : x(f32) -> Hw(x), packed h-pair LDS tile, dword transposed store.
//   k_mid  : per (b,w) slab: staged Haar-H fwd -> MFMA mix (+F residual) ->
//            staged inverse -> store. NEW: launch_bounds(256,4) (4 blk/CU,
//            16 waves) with the B-fragment preload moved AFTER S1 so the
//            128-reg unified cap isn't hit during staging (r6/r7 spilled
//            because Bf was live through S1's peak). Spill tripwire:
//            WRITE_SIZE must stay 131072 KB.
//   k_invW : dword gather -> staged inverse lifting -> y.

namespace {

constexpr float kNorm = 0.70710678118654752440f;

typedef __attribute__((ext_vector_type(8))) short short8;
typedef __attribute__((ext_vector_type(4))) float f32x4;
typedef __attribute__((ext_vector_type(8))) unsigned short ushort8;
typedef __attribute__((ext_vector_type(4))) unsigned int uint4v;

// in-place lifting position -> reference subband position (n=256, 8 levels)
__device__ __forceinline__ int ip2ref(int p) {
  if (p == 0) return 0;
  const int j = __builtin_ctz(p) + 1;
  return (256 >> j) + (p >> j);
}
// reference subband position -> in-place lifting position
__device__ __forceinline__ int ref2ip(int r) {
  if (r == 0) return 0;
  const int tb = 31 - __builtin_clz(r);
  const int j = 8 - tb;
  return ((r - (1 << tb)) << j) | (1 << (j - 1));
}

__device__ __forceinline__ unsigned short f2bf(float f) {  // f32->bf16 RN
  unsigned int u = __float_as_uint(f);
  u += 0x7FFFu + ((u >> 16) & 1u);
  return (unsigned short)(u >> 16);
}
__device__ __forceinline__ float bf2f(unsigned int u) {
  return __uint_as_float((u & 0xFFFFu) << 16);
}
__device__ __forceinline__ unsigned pk2(float lo, float hi) {
  return (unsigned)f2bf(lo) | ((unsigned)f2bf(hi) << 16);
}

// 3-level forward Haar lifting on 8 values (in-place position convention)
__device__ __forceinline__ void lift3f(const float f[8], float o[8]) {
  const float a0 = kNorm * (f[0] + f[1]), d10 = kNorm * (f[0] - f[1]);
  const float a1 = kNorm * (f[2] + f[3]), d11 = kNorm * (f[2] - f[3]);
  const float a2 = kNorm * (f[4] + f[5]), d12 = kNorm * (f[4] - f[5]);
  const float a3 = kNorm * (f[6] + f[7]), d13 = kNorm * (f[6] - f[7]);
  const float b0 = kNorm * (a0 + a1), d20 = kNorm * (a0 - a1);
  const float b1 = kNorm * (a2 + a3), d21 = kNorm * (a2 - a3);
  o[0] = kNorm * (b0 + b1);
  o[4] = kNorm * (b0 - b1);
  o[2] = d20; o[6] = d21;
  o[1] = d10; o[3] = d11; o[5] = d12; o[7] = d13;
}
// inverse of lift3f
__device__ __forceinline__ void ilift3f(const float f[8], float o[8]) {
  const float b0 = kNorm * (f[0] + f[4]), b1 = kNorm * (f[0] - f[4]);
  const float a0 = kNorm * (b0 + f[2]), a1 = kNorm * (b0 - f[2]);
  const float a2 = kNorm * (b1 + f[6]), a3 = kNorm * (b1 - f[6]);
  o[0] = kNorm * (a0 + f[1]); o[1] = kNorm * (a0 - f[1]);
  o[2] = kNorm * (a1 + f[3]); o[3] = kNorm * (a1 - f[3]);
  o[4] = kNorm * (a2 + f[5]); o[5] = kNorm * (a2 - f[5]);
  o[6] = kNorm * (a3 + f[7]); o[7] = kNorm * (a3 - f[7]);
}

// ---------------- Kernel 0: weights -> bf16; v,tau -> packed/permuted -------
__global__ __launch_bounds__(256) void k_prep(const float* __restrict__ cw,
                                              const float* __restrict__ vv,
                                              const float* __restrict__ tt,
                                              unsigned short* __restrict__ wb,
                                              unsigned int* __restrict__ vpk,
                                              unsigned int* __restrict__ tpk) {
  const int idx = blockIdx.x * 256 + threadIdx.x;  // 65536 = 256 w x 256 hp
  if (idx < 8192) wb[idx] = f2bf(cw[idx]);
  const int w = idx >> 8;
  const int hp = idx & 255;                 // in-place h position
  const int off = (ip2ref(hp) << 8) + w;    // reference coord
  vpk[idx] = pk2(vv[off], vv[65536 + off]);
  tpk[idx] = pk2(tt[off], tt[65536 + off]);
}

// ---------------- Kernel 1: forward Haar along W (packed h-pairs) -----------
__global__ __launch_bounds__(256) void k_fwdW(const float* __restrict__ x,
                                              unsigned short* __restrict__ xt) {
  __shared__ unsigned int t[16][260];  // [hd][w] packed (h=2hd lo, 2hd+1 hi)
  const int blk = blockIdx.x;          // img*8 + htile
  const int img = blk >> 3;            // b*64 + c
  const int h0 = (blk & 7) << 5;
  const int tid = threadIdx.x;

  const float* __restrict__ src = x + ((size_t)img << 16) + ((size_t)h0 << 8);
  const int g = tid & 7;
  const int hd = (tid >> 3) & 15;
  const int half = tid >> 7;

  // ---- S1: levels 1-3 in registers, rows 2hd & 2hd+1, b128 LDS writes ----
  const float* __restrict__ r0 = src + (hd << 9);
  const float* __restrict__ r1 = r0 + 256;
#pragma unroll
  for (int it = 0; it < 2; ++it) {
    const int w0 = (g + (half << 3) + (it << 4)) << 3;
    const float4 a0 = *reinterpret_cast<const float4*>(r0 + w0);
    const float4 a1 = *reinterpret_cast<const float4*>(r0 + w0 + 4);
    const float4 b0 = *reinterpret_cast<const float4*>(r1 + w0);
    const float4 b1 = *reinterpret_cast<const float4*>(r1 + w0 + 4);
    float fe[8] = {a0.x, a0.y, a0.z, a0.w, a1.x, a1.y, a1.z, a1.w};
    float fo[8] = {b0.x, b0.y, b0.z, b0.w, b1.x, b1.y, b1.z, b1.w};
    float oe[8], oo[8];
    lift3f(fe, oe);
    lift3f(fo, oo);
    uint4v q0 = {pk2(oe[0], oo[0]), pk2(oe[1], oo[1]),
                 pk2(oe[2], oo[2]), pk2(oe[3], oo[3])};
    uint4v q1 = {pk2(oe[4], oo[4]), pk2(oe[5], oo[5]),
                 pk2(oe[6], oo[6]), pk2(oe[7], oo[7])};
    *reinterpret_cast<uint4v*>(&t[hd][w0]) = q0;
    *reinterpret_cast<uint4v*>(&t[hd][w0 + 4]) = q1;
  }
  __syncthreads();

  // ---- S2: levels 4-6 on stride-8 positions (2q-staggered k order) ----
  if (tid < 64) {
    const int hd2 = tid & 15;
    const int q = tid >> 4;  // 0..3
    const int wq = q << 6;
    unsigned gd[8];
#pragma unroll
    for (int k0 = 0; k0 < 8; ++k0) {
      const int k = (k0 + (q << 1)) & 7;
      gd[k] = t[hd2][wq + (k << 3)];
    }
    float fe[8], fo[8], oe[8], oo[8];
#pragma unroll
    for (int k = 0; k < 8; ++k) {
      fe[k] = bf2f(gd[k]);
      fo[k] = bf2f(gd[k] >> 16);
    }
    lift3f(fe, oe);
    lift3f(fo, oo);
#pragma unroll
    for (int k0 = 0; k0 < 8; ++k0) {
      const int k = (k0 + (q << 1)) & 7;
      t[hd2][wq + (k << 3)] = pk2(oe[k], oo[k]);
    }
  }
  __syncthreads();

  // ---- S3: levels 7-8 on {0,64,128,192} ----
  if (tid < 16) {
    const unsigned d0 = t[tid][0], d1 = t[tid][64];
    const unsigned d2 = t[tid][128], d3 = t[tid][192];
    const float e0 = bf2f(d0), e1 = bf2f(d1), e2 = bf2f(d2), e3 = bf2f(d3);
    const float p0 = bf2f(d0 >> 16), p1 = bf2f(d1 >> 16);
    const float p2 = bf2f(d2 >> 16), p3 = bf2f(d3 >> 16);
    const float ae0 = kNorm * (e0 + e1), de0 = kNorm * (e0 - e1);
    const float ae1 = kNorm * (e2 + e3), de1 = kNorm * (e2 - e3);
    const float ao0 = kNorm * (p0 + p1), do0 = kNorm * (p0 - p1);
    const float ao1 = kNorm * (p2 + p3), do1 = kNorm * (p2 - p3);
    t[tid][0] = pk2(kNorm * (ae0 + ae1), kNorm * (ao0 + ao1));
    t[tid][64] = pk2(de0, do0);
    t[tid][128] = pk2(kNorm * (ae0 - ae1), kNorm * (ao0 - ao1));
    t[tid][192] = pk2(de1, do1);
  }
  __syncthreads();

  // ---- transposed+permuted store: pure dword copy (already bf16 pairs) ----
  unsigned short* __restrict__ dst = xt + ((size_t)img << 16) + h0;
#pragma unroll
  for (int k = 0; k < 4; ++k) {
    const int idx = (k << 8) + tid;
    const int wp = idx >> 2;          // in-place w
    const int hq = (idx & 3) << 2;    // dword base: 0,4,8,12 (h = 2hq..2hq+7)
    const int wr = ip2ref(wp);
    uint4v qv = {t[hq][wp], t[hq + 1][wp], t[hq + 2][wp], t[hq + 3][wp]};
    *reinterpret_cast<uint4v*>(dst + ((size_t)wr << 8) + (hq << 1)) = qv;
  }
}

// ---------------- Kernel 2: staged Haar-H + MFMA mix (h-major packed LDS) ---
// tile dword (h, cdw): dwidx = h*32 + ((cdw + 4*(h&7) + 8*((h>>3)&3)) & 31)
__device__ __forceinline__ int swzc(int h, int cdw) {
  return (h << 5) | ((cdw + ((h & 7) << 2) + (((h >> 3) & 3) << 3)) & 31);
}

__global__ __launch_bounds__(256, 4) void k_mid(
    unsigned short* __restrict__ ws, const unsigned short* __restrict__ wb,
    const unsigned int* __restrict__ vpk, const unsigned int* __restrict__ tpk) {
  __shared__ unsigned int t32[8192];  // 32 KiB: [h=256][cdw=32] swizzled
  __shared__ unsigned int vt[512];    // [0..255]=v packed, [256..511]=tau packed
  unsigned short* t16 = reinterpret_cast<unsigned short*>(t32);

  const int blk = blockIdx.x;  // b*256 + w
  const int b = blk >> 8;
  const int w = blk & 255;
  const int tid = threadIdx.x;

  unsigned short* __restrict__ base = ws + ((size_t)b << 22) + ((size_t)w << 8);

  // stage v/tau (coalesced; already ip2ref-permuted by k_prep)
  vt[tid] = vpk[(w << 8) + tid];
  vt[256 + tid] = tpk[(w << 8) + tid];

  // ---- S1: global->reg, fwd levels 1-3 in registers, write tile ----
  // (B-fragment preload deliberately NOT here: keeps S1's live set small so
  //  launch_bounds(256,4)'s 128-reg unified cap doesn't force spills.)
  const int cdw = tid >> 3;  // 0..31 (channel pair)
  const int c0 = cdw << 1;
  const int o8 = tid & 7;
#pragma unroll
  for (int it = 0; it < 4; ++it) {
    const int h0 = (o8 << 3) + (it << 6);
    const ushort8 rA =
        *reinterpret_cast<const ushort8*>(base + ((size_t)c0 << 16) + h0);
    const ushort8 rB =
        *reinterpret_cast<const ushort8*>(base + ((size_t)(c0 + 1) << 16) + h0);
    float fa[8], fb[8], oa[8], ob[8];
#pragma unroll
    for (int j = 0; j < 8; ++j) {
      fa[j] = bf2f(rA[j]);
      fb[j] = bf2f(rB[j]);
    }
    lift3f(fa, oa);
    lift3f(fb, ob);
#pragma unroll
    for (int j = 0; j < 8; ++j) t32[swzc(h0 + j, cdw)] = pk2(oa[j], ob[j]);
  }
  __syncthreads();

  // ---- B-fragment preload (mt-invariant): issued here so the loads fly
  //      while tid<128 / tid<32 waves do S2/S3 ----
  const int l15 = tid & 15;
  const int l4 = (tid & 63) >> 4;
  short8 Bf[4][4];
#pragma unroll
  for (int og = 0; og < 4; ++og) {
    const int o = (og << 4) + l15;
    const unsigned short* wr0 = wb + (o << 6) + (l4 << 3);         // p=0
    const unsigned short* wr1 = wb + 4096 + (o << 6) + (l4 << 3);  // p=1
    Bf[og][0] = *reinterpret_cast<const short8*>(wr0);
    Bf[og][1] = *reinterpret_cast<const short8*>(wr0 + 32);
    Bf[og][2] = *reinterpret_cast<const short8*>(wr1);
    Bf[og][3] = *reinterpret_cast<const short8*>(wr1 + 32);
  }

  // ---- S2: fwd levels 4-6 (8 values @ stride 8), 128 threads ----
  if (tid < 128) {
    const int cd = tid & 31;
    const int h0 = (tid >> 5) << 6;
    unsigned int g[8];
#pragma unroll
    for (int k = 0; k < 8; ++k) g[k] = t32[swzc(h0 + (k << 3), cd)];
    float fa[8], fb[8], oa[8], ob[8];
#pragma unroll
    for (int k = 0; k < 8; ++k) {
      fa[k] = bf2f(g[k]);
      fb[k] = bf2f(g[k] >> 16);
    }
    lift3f(fa, oa);
    lift3f(fb, ob);
#pragma unroll
    for (int k = 0; k < 8; ++k)
      t32[swzc(h0 + (k << 3), cd)] = pk2(oa[k], ob[k]);
  }
  __syncthreads();

  // ---- S3: fwd levels 7-8 (4 values @ stride 64), 32 threads ----
  if (tid < 32) {
    unsigned int g[4];
#pragma unroll
    for (int k = 0; k < 4; ++k) g[k] = t32[swzc(k << 6, tid)];
    float fa[4], fb[4];
#pragma unroll
    for (int k = 0; k < 4; ++k) {
      fa[k] = bf2f(g[k]);
      fb[k] = bf2f(g[k] >> 16);
    }
    const float aa0 = kNorm * (fa[0] + fa[1]), da0 = kNorm * (fa[0] - fa[1]);
    const float aa1 = kNorm * (fa[2] + fa[3]), da1 = kNorm * (fa[2] - fa[3]);
    const float ab0 = kNorm * (fb[0] + fb[1]), db0 = kNorm * (fb[0] - fb[1]);
    const float ab1 = kNorm * (fb[2] + fb[3]), db1 = kNorm * (fb[2] - fb[3]);
    t32[swzc(0, tid)] = pk2(kNorm * (aa0 + aa1), kNorm * (ab0 + ab1));
    t32[swzc(64, tid)] = pk2(da0, db0);
    t32[swzc(128, tid)] = pk2(kNorm * (aa0 - aa1), kNorm * (ab0 - ab1));
    t32[swzc(192, tid)] = pk2(da1, db1);
  }
  __syncthreads();

  // ---- GEMM + fused epilogue (acc + F residual), per-wave 64-row strip ----
  const int strip = (tid >> 6) << 6;
#pragma unroll 1
  for (int mt = 0; mt < 4; ++mt) {
    const int hh = strip + (mt << 4) + l15;
    const short8 a0 =
        *reinterpret_cast<const short8*>(&t32[swzc(hh, l4 << 2)]);
    const short8 a1 =
        *reinterpret_cast<const short8*>(&t32[swzc(hh, 16 + (l4 << 2))]);
    const int hb = strip + (mt << 4) + (l4 << 2);
    const uint4v vq = *reinterpret_cast<const uint4v*>(&vt[hb]);
    const uint4v tq = *reinterpret_cast<const uint4v*>(&vt[256 + hb]);
#pragma unroll
    for (int og = 0; og < 4; ++og) {
      const int o = (og << 4) + l15;
      f32x4 accL = {0.f, 0.f, 0.f, 0.f};
      f32x4 accH = {0.f, 0.f, 0.f, 0.f};
      accL = __builtin_amdgcn_mfma_f32_16x16x32_bf16(a0, Bf[og][0], accL, 0, 0, 0);
      accH = __builtin_amdgcn_mfma_f32_16x16x32_bf16(a0, Bf[og][2], accH, 0, 0, 0);
      accL = __builtin_amdgcn_mfma_f32_16x16x32_bf16(a1, Bf[og][1], accL, 0, 0, 0);
      accH = __builtin_amdgcn_mfma_f32_16x16x32_bf16(a1, Bf[og][3], accH, 0, 0, 0);
#pragma unroll
      for (int r = 0; r < 4; ++r) {
        const float v0 = bf2f(vq[r]), v1 = bf2f(vq[r] >> 16);
        const float t0 = bf2f(tq[r]), t1 = bf2f(tq[r] >> 16);
        const float g0 = accL[r] * v0;
        const float g1 = accH[r] * v1;
        float rr = 0.f;
        const float q0 = fabsf(g0) - t0;
        if (q0 > 0.f) rr += copysignf(q0, g0);
        const float q1 = fabsf(g1) - t1;
        if (q1 > 0.f) rr += copysignf(q1, g1);
        const int idx16 = (swzc(hb + r, o >> 1) << 1) | (o & 1);
        const float Fv = bf2f(t16[idx16]);  // residual in wavelet domain
        t16[idx16] = f2bf(rr + Fv);
      }
    }
  }
  __syncthreads();

  // ---- inverse S3: levels 8,7 ----
  if (tid < 32) {
    unsigned int g[4];
#pragma unroll
    for (int k = 0; k < 4; ++k) g[k] = t32[swzc(k << 6, tid)];
    float fa[4], fb[4];
#pragma unroll
    for (int k = 0; k < 4; ++k) {
      fa[k] = bf2f(g[k]);
      fb[k] = bf2f(g[k] >> 16);
    }
    const float ua0 = kNorm * (fa[0] + fa[2]), ua1 = kNorm * (fa[0] - fa[2]);
    const float ub0 = kNorm * (fb[0] + fb[2]), ub1 = kNorm * (fb[0] - fb[2]);
    t32[swzc(0, tid)] = pk2(kNorm * (ua0 + fa[1]), kNorm * (ub0 + fb[1]));
    t32[swzc(64, tid)] = pk2(kNorm * (ua0 - fa[1]), kNorm * (ub0 - fb[1]));
    t32[swzc(128, tid)] = pk2(kNorm * (ua1 + fa[3]), kNorm * (ub1 + fb[3]));
    t32[swzc(192, tid)] = pk2(kNorm * (ua1 - fa[3]), kNorm * (ub1 - fb[3]));
  }
  __syncthreads();

  // ---- inverse S2: levels 6,5,4 ----
  if (tid < 128) {
    const int cd = tid & 31;
    const int h0 = (tid >> 5) << 6;
    unsigned int g[8];
#pragma unroll
    for (int k = 0; k < 8; ++k) g[k] = t32[swzc(h0 + (k << 3), cd)];
    float fa[8], fb[8], oa[8], ob[8];
#pragma unroll
    for (int k = 0; k < 8; ++k) {
      fa[k] = bf2f(g[k]);
      fb[k] = bf2f(g[k] >> 16);
    }
    ilift3f(fa, oa);
    ilift3f(fb, ob);
#pragma unroll
    for (int k = 0; k < 8; ++k)
      t32[swzc(h0 + (k << 3), cd)] = pk2(oa[k], ob[k]);
  }
  __syncthreads();

  // ---- inverse S1: levels 3,2,1 in registers + global store ----
#pragma unroll
  for (int it = 0; it < 4; ++it) {
    const int h0 = (o8 << 3) + (it << 6);
    unsigned int g[8];
#pragma unroll
    for (int j = 0; j < 8; ++j) g[j] = t32[swzc(h0 + j, cdw)];
    float fa[8], fb[8], oa[8], ob[8];
#pragma unroll
    for (int j = 0; j < 8; ++j) {
      fa[j] = bf2f(g[j]);
      fb[j] = bf2f(g[j] >> 16);
    }
    ilift3f(fa, oa);
    ilift3f(fb, ob);
    ushort8 sA, sB;
#pragma unroll
    for (int j = 0; j < 8; ++j) {
      sA[j] = f2bf(oa[j]);
      sB[j] = f2bf(ob[j]);
    }
    *reinterpret_cast<ushort8*>(base + ((size_t)c0 << 16) + h0) = sA;
    *reinterpret_cast<ushort8*>(base + ((size_t)(c0 + 1) << 16) + h0) = sB;
  }
}

// ---------------- Kernel 3: inverse Haar along W (packed h-pairs) -> y ------
__global__ __launch_bounds__(256) void k_invW(const unsigned short* __restrict__ at,
                                              float* __restrict__ y) {
  __shared__ unsigned int t[16][260];  // [hd][w in-place] packed h-pairs
  const int blk = blockIdx.x;          // img*8 + htile
  const int img = blk >> 3;
  const int h0 = (blk & 7) << 5;
  const int tid = threadIdx.x;

  // ---- gather: pure dword copy (ws already bf16 h-pairs) ----
  const unsigned short* __restrict__ basep = at + ((size_t)img << 16) + h0;
#pragma unroll
  for (int k = 0; k < 4; ++k) {
    const int idx = (k << 8) + tid;
    const int wp = idx >> 2;
    const int hq = (idx & 3) << 2;
    const int wr = ip2ref(wp);
    const uint4v qv = *reinterpret_cast<const uint4v*>(
        basep + ((size_t)wr << 8) + (hq << 1));
    t[hq][wp] = qv[0];
    t[hq + 1][wp] = qv[1];
    t[hq + 2][wp] = qv[2];
    t[hq + 3][wp] = qv[3];
  }
  __syncthreads();

  // ---- inverse S3: levels 8,7 on {0,64,128,192} ----
  if (tid < 16) {
    const unsigned d0 = t[tid][0], d1 = t[tid][64];
    const unsigned d2 = t[tid][128], d3 = t[tid][192];
    const float e0 = bf2f(d0), e1 = bf2f(d1), e2 = bf2f(d2), e3 = bf2f(d3);
    const float p0 = bf2f(d0 >> 16), p1 = bf2f(d1 >> 16);
    const float p2 = bf2f(d2 >> 16), p3 = bf2f(d3 >> 16);
    const float ue0 = kNorm * (e0 + e2), ue1 = kNorm * (e0 - e2);
    const float uo0 = kNorm * (p0 + p2), uo1 = kNorm * (p0 - p2);
    t[tid][0] = pk2(kNorm * (ue0 + e1), kNorm * (uo0 + p1));
    t[tid][64] = pk2(kNorm * (ue0 - e1), kNorm * (uo0 - p1));
    t[tid][128] = pk2(kNorm * (ue1 + e3), kNorm * (uo1 + p3));
    t[tid][192] = pk2(kNorm * (ue1 - e3), kNorm * (uo1 - p3));
  }
  __syncthreads();

  // ---- inverse S2: levels 6,5,4 on stride-8 positions (staggered) ----
  if (tid < 64) {
    const int hd2 = tid & 15;
    const int q = tid >> 4;
    const int wq = q << 6;
    unsigned gd[8];
#pragma unroll
    for (int k0 = 0; k0 < 8; ++k0) {
      const int k = (k0 + (q << 1)) & 7;
      gd[k] = t[hd2][wq + (k << 3)];
    }
    float fe[8], fo[8], oe[8], oo[8];
#pragma unroll
    for (int k = 0; k < 8; ++k) {
      fe[k] = bf2f(gd[k]);
      fo[k] = bf2f(gd[k] >> 16);
    }
    ilift3f(fe, oe);
    ilift3f(fo, oo);
#pragma unroll
    for (int k0 = 0; k0 < 8; ++k0) {
      const int k = (k0 + (q << 1)) & 7;
      t[hd2][wq + (k << 3)] = pk2(oe[k], oo[k]);
    }
  }
  __syncthreads();

  // ---- inverse S1: levels 3,2,1 in registers, y store (rows 2hd, 2hd+1) ----
  const int g = tid & 7;
  const int hd = (tid >> 3) & 15;
  const int half = tid >> 7;
  float* __restrict__ yr0 =
      y + ((size_t)img << 16) + ((size_t)h0 << 8) + (hd << 9);
  float* __restrict__ yr1 = yr0 + 256;
#pragma unroll
  for (int it = 0; it < 2; ++it) {
    const int w0 = (g + (half << 3) + (it << 4)) << 3;
    const uint4v qa = *reinterpret_cast<const uint4v*>(&t[hd][w0]);
    const uint4v qb = *reinterpret_cast<const uint4v*>(&t[hd][w0 + 4]);
    float fe[8], fo[8], oe[8], oo[8];
#pragma unroll
    for (int j = 0; j < 4; ++j) {
      fe[j] = bf2f(qa[j]);
      fo[j] = bf2f(qa[j] >> 16);
      fe[4 + j] = bf2f(qb[j]);
      fo[4 + j] = bf2f(qb[j] >> 16);
    }
    ilift3f(fe, oe);
    ilift3f(fo, oo);
    float4 ya0 = {oe[0], oe[1], oe[2], oe[3]};
    float4 ya1 = {oe[4], oe[5], oe[6], oe[7]};
    float4 yb0 = {oo[0], oo[1], oo[2], oo[3]};
    float4 yb1 = {oo[4], oo[5], oo[6], oo[7]};
    *reinterpret_cast<float4*>(yr0 + w0) = ya0;
    *reinterpret_cast<float4*>(yr0 + w0 + 4) = ya1;
    *reinterpret_cast<float4*>(yr1 + w0) = yb0;
    *reinterpret_cast<float4*>(yr1 + w0 + 4) = yb1;
  }
}

}  // namespace

extern "C" void kernel_launch(void* const* d_in, const int* in_sizes, int n_in,
                              void* d_out, int out_size, void* d_ws, size_t ws_size,
                              hipStream_t stream) {
  (void)in_sizes; (void)n_in; (void)out_size; (void)ws_size;
  const float* x  = (const float*)d_in[0];
  const float* vv = (const float*)d_in[1];
  const float* cw = (const float*)d_in[2];
  const float* tt = (const float*)d_in[3];
  float* y = (float*)d_out;
  unsigned short* ws = (unsigned short*)d_ws;      // 128 MiB bf16 slab
  unsigned short* wb = ws + ((size_t)64 << 20);    // bf16 weights (16 KiB)
  unsigned int* vpk = (unsigned int*)(ws + ((size_t)64 << 20) + 16384);
  unsigned int* tpk = vpk + 65536;                 // 256 KiB each

  k_prep<<<256, 256, 0, stream>>>(cw, vv, tt, wb, vpk, tpk);
  k_fwdW<<<8192, 256, 0, stream>>>(x, ws);
  k_mid <<<4096, 256, 0, stream>>>(ws, wb, vpk, tpk);
  k_invW<<<8192, 256, 0, stream>>>(ws, y);
}

// Round 14
// 323.548 us; speedup vs baseline: 1.0005x; 1.0005x over previous
//
#include <hip/hip_runtime.h>
#include <hip/hip_bf16.h>

// Problem: B=16, C=64, H=256, W=256, P=2
// y = haar2d_inv( sum_p softthr( (haar2d(x)*v_p) @ w_p^T, tau_p ) ) + x
// Residual folded in wavelet domain: y = invHaar2d(acc + Haar2d(x)).
//
// ws: bf16 (b,c,wref,h) slab (128 MiB) + bf16 weights + packed/permuted v,tau.
//   k_prep : conv_w->bf16; v,tau -> bf16x2 packed, [w][h_inplace] layout
//   k_fwdW : x(f32) -> Hw(x), packed h-pair LDS tile, dword transposed store.
//   k_mid  : per (b,w) slab: staged Haar-H fwd -> MFMA mix (+F residual) ->
//            staged inverse -> store. launch_bounds(256,4) with the Bf
//            preload pinned AFTER S1 by sched_barrier(0): r13 spilled
//            because the scheduler hoisted the 16 weight loads back across
//            the barrier (s_barrier doesn't order restrict-const global
//            loads), putting Bf(64) live through S1's staging peak.
//            Spill tripwire: k_mid WRITE_SIZE must be 131072 KB.
//   k_invW : dword gather -> staged inverse lifting -> y.

namespace {

constexpr float kNorm = 0.70710678118654752440f;

typedef __attribute__((ext_vector_type(8))) short short8;
typedef __attribute__((ext_vector_type(4))) float f32x4;
typedef __attribute__((ext_vector_type(8))) unsigned short ushort8;
typedef __attribute__((ext_vector_type(4))) unsigned int uint4v;

// in-place lifting position -> reference subband position (n=256, 8 levels)
__device__ __forceinline__ int ip2ref(int p) {
  if (p == 0) return 0;
  const int j = __builtin_ctz(p) + 1;
  return (256 >> j) + (p >> j);
}
// reference subband position -> in-place lifting position
__device__ __forceinline__ int ref2ip(int r) {
  if (r == 0) return 0;
  const int tb = 31 - __builtin_clz(r);
  const int j = 8 - tb;
  return ((r - (1 << tb)) << j) | (1 << (j - 1));
}

__device__ __forceinline__ unsigned short f2bf(float f) {  // f32->bf16 RN
  unsigned int u = __float_as_uint(f);
  u += 0x7FFFu + ((u >> 16) & 1u);
  return (unsigned short)(u >> 16);
}
__device__ __forceinline__ float bf2f(unsigned int u) {
  return __uint_as_float((u & 0xFFFFu) << 16);
}
__device__ __forceinline__ unsigned pk2(float lo, float hi) {
  return (unsigned)f2bf(lo) | ((unsigned)f2bf(hi) << 16);
}

// 3-level forward Haar lifting on 8 values (in-place position convention)
__device__ __forceinline__ void lift3f(const float f[8], float o[8]) {
  const float a0 = kNorm * (f[0] + f[1]), d10 = kNorm * (f[0] - f[1]);
  const float a1 = kNorm * (f[2] + f[3]), d11 = kNorm * (f[2] - f[3]);
  const float a2 = kNorm * (f[4] + f[5]), d12 = kNorm * (f[4] - f[5]);
  const float a3 = kNorm * (f[6] + f[7]), d13 = kNorm * (f[6] - f[7]);
  const float b0 = kNorm * (a0 + a1), d20 = kNorm * (a0 - a1);
  const float b1 = kNorm * (a2 + a3), d21 = kNorm * (a2 - a3);
  o[0] = kNorm * (b0 + b1);
  o[4] = kNorm * (b0 - b1);
  o[2] = d20; o[6] = d21;
  o[1] = d10; o[3] = d11; o[5] = d12; o[7] = d13;
}
// inverse of lift3f
__device__ __forceinline__ void ilift3f(const float f[8], float o[8]) {
  const float b0 = kNorm * (f[0] + f[4]), b1 = kNorm * (f[0] - f[4]);
  const float a0 = kNorm * (b0 + f[2]), a1 = kNorm * (b0 - f[2]);
  const float a2 = kNorm * (b1 + f[6]), a3 = kNorm * (b1 - f[6]);
  o[0] = kNorm * (a0 + f[1]); o[1] = kNorm * (a0 - f[1]);
  o[2] = kNorm * (a1 + f[3]); o[3] = kNorm * (a1 - f[3]);
  o[4] = kNorm * (a2 + f[5]); o[5] = kNorm * (a2 - f[5]);
  o[6] = kNorm * (a3 + f[7]); o[7] = kNorm * (a3 - f[7]);
}

// ---------------- Kernel 0: weights -> bf16; v,tau -> packed/permuted -------
__global__ __launch_bounds__(256) void k_prep(const float* __restrict__ cw,
                                              const float* __restrict__ vv,
                                              const float* __restrict__ tt,
                                              unsigned short* __restrict__ wb,
                                              unsigned int* __restrict__ vpk,
                                              unsigned int* __restrict__ tpk) {
  const int idx = blockIdx.x * 256 + threadIdx.x;  // 65536 = 256 w x 256 hp
  if (idx < 8192) wb[idx] = f2bf(cw[idx]);
  const int w = idx >> 8;
  const int hp = idx & 255;                 // in-place h position
  const int off = (ip2ref(hp) << 8) + w;    // reference coord
  vpk[idx] = pk2(vv[off], vv[65536 + off]);
  tpk[idx] = pk2(tt[off], tt[65536 + off]);
}

// ---------------- Kernel 1: forward Haar along W (packed h-pairs) -----------
__global__ __launch_bounds__(256) void k_fwdW(const float* __restrict__ x,
                                              unsigned short* __restrict__ xt) {
  __shared__ unsigned int t[16][260];  // [hd][w] packed (h=2hd lo, 2hd+1 hi)
  const int blk = blockIdx.x;          // img*8 + htile
  const int img = blk >> 3;            // b*64 + c
  const int h0 = (blk & 7) << 5;
  const int tid = threadIdx.x;

  const float* __restrict__ src = x + ((size_t)img << 16) + ((size_t)h0 << 8);
  const int g = tid & 7;
  const int hd = (tid >> 3) & 15;
  const int half = tid >> 7;

  // ---- S1: levels 1-3 in registers, rows 2hd & 2hd+1, b128 LDS writes ----
  const float* __restrict__ r0 = src + (hd << 9);
  const float* __restrict__ r1 = r0 + 256;
#pragma unroll
  for (int it = 0; it < 2; ++it) {
    const int w0 = (g + (half << 3) + (it << 4)) << 3;
    const float4 a0 = *reinterpret_cast<const float4*>(r0 + w0);
    const float4 a1 = *reinterpret_cast<const float4*>(r0 + w0 + 4);
    const float4 b0 = *reinterpret_cast<const float4*>(r1 + w0);
    const float4 b1 = *reinterpret_cast<const float4*>(r1 + w0 + 4);
    float fe[8] = {a0.x, a0.y, a0.z, a0.w, a1.x, a1.y, a1.z, a1.w};
    float fo[8] = {b0.x, b0.y, b0.z, b0.w, b1.x, b1.y, b1.z, b1.w};
    float oe[8], oo[8];
    lift3f(fe, oe);
    lift3f(fo, oo);
    uint4v q0 = {pk2(oe[0], oo[0]), pk2(oe[1], oo[1]),
                 pk2(oe[2], oo[2]), pk2(oe[3], oo[3])};
    uint4v q1 = {pk2(oe[4], oo[4]), pk2(oe[5], oo[5]),
                 pk2(oe[6], oo[6]), pk2(oe[7], oo[7])};
    *reinterpret_cast<uint4v*>(&t[hd][w0]) = q0;
    *reinterpret_cast<uint4v*>(&t[hd][w0 + 4]) = q1;
  }
  __syncthreads();

  // ---- S2: levels 4-6 on stride-8 positions (2q-staggered k order) ----
  if (tid < 64) {
    const int hd2 = tid & 15;
    const int q = tid >> 4;  // 0..3
    const int wq = q << 6;
    unsigned gd[8];
#pragma unroll
    for (int k0 = 0; k0 < 8; ++k0) {
      const int k = (k0 + (q << 1)) & 7;
      gd[k] = t[hd2][wq + (k << 3)];
    }
    float fe[8], fo[8], oe[8], oo[8];
#pragma unroll
    for (int k = 0; k < 8; ++k) {
      fe[k] = bf2f(gd[k]);
      fo[k] = bf2f(gd[k] >> 16);
    }
    lift3f(fe, oe);
    lift3f(fo, oo);
#pragma unroll
    for (int k0 = 0; k0 < 8; ++k0) {
      const int k = (k0 + (q << 1)) & 7;
      t[hd2][wq + (k << 3)] = pk2(oe[k], oo[k]);
    }
  }
  __syncthreads();

  // ---- S3: levels 7-8 on {0,64,128,192} ----
  if (tid < 16) {
    const unsigned d0 = t[tid][0], d1 = t[tid][64];
    const unsigned d2 = t[tid][128], d3 = t[tid][192];
    const float e0 = bf2f(d0), e1 = bf2f(d1), e2 = bf2f(d2), e3 = bf2f(d3);
    const float p0 = bf2f(d0 >> 16), p1 = bf2f(d1 >> 16);
    const float p2 = bf2f(d2 >> 16), p3 = bf2f(d3 >> 16);
    const float ae0 = kNorm * (e0 + e1), de0 = kNorm * (e0 - e1);
    const float ae1 = kNorm * (e2 + e3), de1 = kNorm * (e2 - e3);
    const float ao0 = kNorm * (p0 + p1), do0 = kNorm * (p0 - p1);
    const float ao1 = kNorm * (p2 + p3), do1 = kNorm * (p2 - p3);
    t[tid][0] = pk2(kNorm * (ae0 + ae1), kNorm * (ao0 + ao1));
    t[tid][64] = pk2(de0, do0);
    t[tid][128] = pk2(kNorm * (ae0 - ae1), kNorm * (ao0 - ao1));
    t[tid][192] = pk2(de1, do1);
  }
  __syncthreads();

  // ---- transposed+permuted store: pure dword copy (already bf16 pairs) ----
  unsigned short* __restrict__ dst = xt + ((size_t)img << 16) + h0;
#pragma unroll
  for (int k = 0; k < 4; ++k) {
    const int idx = (k << 8) + tid;
    const int wp = idx >> 2;          // in-place w
    const int hq = (idx & 3) << 2;    // dword base: 0,4,8,12 (h = 2hq..2hq+7)
    const int wr = ip2ref(wp);
    uint4v qv = {t[hq][wp], t[hq + 1][wp], t[hq + 2][wp], t[hq + 3][wp]};
    *reinterpret_cast<uint4v*>(dst + ((size_t)wr << 8) + (hq << 1)) = qv;
  }
}

// ---------------- Kernel 2: staged Haar-H + MFMA mix (h-major packed LDS) ---
// tile dword (h, cdw): dwidx = h*32 + ((cdw + 4*(h&7) + 8*((h>>3)&3)) & 31)
__device__ __forceinline__ int swzc(int h, int cdw) {
  return (h << 5) | ((cdw + ((h & 7) << 2) + (((h >> 3) & 3) << 3)) & 31);
}

__global__ __launch_bounds__(256, 4) void k_mid(
    unsigned short* __restrict__ ws, const unsigned short* __restrict__ wb,
    const unsigned int* __restrict__ vpk, const unsigned int* __restrict__ tpk) {
  __shared__ unsigned int t32[8192];  // 32 KiB: [h=256][cdw=32] swizzled
  __shared__ unsigned int vt[512];    // [0..255]=v packed, [256..511]=tau packed
  unsigned short* t16 = reinterpret_cast<unsigned short*>(t32);

  const int blk = blockIdx.x;  // b*256 + w
  const int b = blk >> 8;
  const int w = blk & 255;
  const int tid = threadIdx.x;

  unsigned short* __restrict__ base = ws + ((size_t)b << 22) + ((size_t)w << 8);

  // stage v/tau (coalesced; already ip2ref-permuted by k_prep)
  vt[tid] = vpk[(w << 8) + tid];
  vt[256 + tid] = tpk[(w << 8) + tid];

  // ---- S1: global->reg, fwd levels 1-3 in registers, write tile ----
  const int cdw = tid >> 3;  // 0..31 (channel pair)
  const int c0 = cdw << 1;
  const int o8 = tid & 7;
#pragma unroll
  for (int it = 0; it < 4; ++it) {
    const int h0 = (o8 << 3) + (it << 6);
    const ushort8 rA =
        *reinterpret_cast<const ushort8*>(base + ((size_t)c0 << 16) + h0);
    const ushort8 rB =
        *reinterpret_cast<const ushort8*>(base + ((size_t)(c0 + 1) << 16) + h0);
    float fa[8], fb[8], oa[8], ob[8];
#pragma unroll
    for (int j = 0; j < 8; ++j) {
      fa[j] = bf2f(rA[j]);
      fb[j] = bf2f(rB[j]);
    }
    lift3f(fa, oa);
    lift3f(fb, ob);
#pragma unroll
    for (int j = 0; j < 8; ++j) t32[swzc(h0 + j, cdw)] = pk2(oa[j], ob[j]);
  }
  __syncthreads();

  // ---- B-fragment preload, PINNED here by sched_barrier(0) so the
  //      scheduler cannot hoist the 16 loads back into S1's register peak
  //      (r13's spill mechanism). Loads then fly while S2/S3 compute. ----
  __builtin_amdgcn_sched_barrier(0);
  const int l15 = tid & 15;
  const int l4 = (tid & 63) >> 4;
  short8 Bf[4][4];
#pragma unroll
  for (int og = 0; og < 4; ++og) {
    const int o = (og << 4) + l15;
    const unsigned short* wr0 = wb + (o << 6) + (l4 << 3);         // p=0
    const unsigned short* wr1 = wb + 4096 + (o << 6) + (l4 << 3);  // p=1
    Bf[og][0] = *reinterpret_cast<const short8*>(wr0);
    Bf[og][1] = *reinterpret_cast<const short8*>(wr0 + 32);
    Bf[og][2] = *reinterpret_cast<const short8*>(wr1);
    Bf[og][3] = *reinterpret_cast<const short8*>(wr1 + 32);
  }
  __builtin_amdgcn_sched_barrier(0);

  // ---- S2: fwd levels 4-6 (8 values @ stride 8), 128 threads ----
  if (tid < 128) {
    const int cd = tid & 31;
    const int h0 = (tid >> 5) << 6;
    unsigned int g[8];
#pragma unroll
    for (int k = 0; k < 8; ++k) g[k] = t32[swzc(h0 + (k << 3), cd)];
    float fa[8], fb[8], oa[8], ob[8];
#pragma unroll
    for (int k = 0; k < 8; ++k) {
      fa[k] = bf2f(g[k]);
      fb[k] = bf2f(g[k] >> 16);
    }
    lift3f(fa, oa);
    lift3f(fb, ob);
#pragma unroll
    for (int k = 0; k < 8; ++k)
      t32[swzc(h0 + (k << 3), cd)] = pk2(oa[k], ob[k]);
  }
  __syncthreads();

  // ---- S3: fwd levels 7-8 (4 values @ stride 64), 32 threads ----
  if (tid < 32) {
    unsigned int g[4];
#pragma unroll
    for (int k = 0; k < 4; ++k) g[k] = t32[swzc(k << 6, tid)];
    float fa[4], fb[4];
#pragma unroll
    for (int k = 0; k < 4; ++k) {
      fa[k] = bf2f(g[k]);
      fb[k] = bf2f(g[k] >> 16);
    }
    const float aa0 = kNorm * (fa[0] + fa[1]), da0 = kNorm * (fa[0] - fa[1]);
    const float aa1 = kNorm * (fa[2] + fa[3]), da1 = kNorm * (fa[2] - fa[3]);
    const float ab0 = kNorm * (fb[0] + fb[1]), db0 = kNorm * (fb[0] - fb[1]);
    const float ab1 = kNorm * (fb[2] + fb[3]), db1 = kNorm * (fb[2] - fb[3]);
    t32[swzc(0, tid)] = pk2(kNorm * (aa0 + aa1), kNorm * (ab0 + ab1));
    t32[swzc(64, tid)] = pk2(da0, db0);
    t32[swzc(128, tid)] = pk2(kNorm * (aa0 - aa1), kNorm * (ab0 - ab1));
    t32[swzc(192, tid)] = pk2(da1, db1);
  }
  __syncthreads();

  // ---- GEMM + fused epilogue (acc + F residual), per-wave 64-row strip ----
  const int strip = (tid >> 6) << 6;
#pragma unroll 1
  for (int mt = 0; mt < 4; ++mt) {
    const int hh = strip + (mt << 4) + l15;
    const short8 a0 =
        *reinterpret_cast<const short8*>(&t32[swzc(hh, l4 << 2)]);
    const short8 a1 =
        *reinterpret_cast<const short8*>(&t32[swzc(hh, 16 + (l4 << 2))]);
    const int hb = strip + (mt << 4) + (l4 << 2);
    const uint4v vq = *reinterpret_cast<const uint4v*>(&vt[hb]);
    const uint4v tq = *reinterpret_cast<const uint4v*>(&vt[256 + hb]);
#pragma unroll
    for (int og = 0; og < 4; ++og) {
      const int o = (og << 4) + l15;
      f32x4 accL = {0.f, 0.f, 0.f, 0.f};
      f32x4 accH = {0.f, 0.f, 0.f, 0.f};
      accL = __builtin_amdgcn_mfma_f32_16x16x32_bf16(a0, Bf[og][0], accL, 0, 0, 0);
      accH = __builtin_amdgcn_mfma_f32_16x16x32_bf16(a0, Bf[og][2], accH, 0, 0, 0);
      accL = __builtin_amdgcn_mfma_f32_16x16x32_bf16(a1, Bf[og][1], accL, 0, 0, 0);
      accH = __builtin_amdgcn_mfma_f32_16x16x32_bf16(a1, Bf[og][3], accH, 0, 0, 0);
#pragma unroll
      for (int r = 0; r < 4; ++r) {
        const float v0 = bf2f(vq[r]), v1 = bf2f(vq[r] >> 16);
        const float t0 = bf2f(tq[r]), t1 = bf2f(tq[r] >> 16);
        const float g0 = accL[r] * v0;
        const float g1 = accH[r] * v1;
        float rr = 0.f;
        const float q0 = fabsf(g0) - t0;
        if (q0 > 0.f) rr += copysignf(q0, g0);
        const float q1 = fabsf(g1) - t1;
        if (q1 > 0.f) rr += copysignf(q1, g1);
        const int idx16 = (swzc(hb + r, o >> 1) << 1) | (o & 1);
        const float Fv = bf2f(t16[idx16]);  // residual in wavelet domain
        t16[idx16] = f2bf(rr + Fv);
      }
    }
  }
  __syncthreads();

  // ---- inverse S3: levels 8,7 ----
  if (tid < 32) {
    unsigned int g[4];
#pragma unroll
    for (int k = 0; k < 4; ++k) g[k] = t32[swzc(k << 6, tid)];
    float fa[4], fb[4];
#pragma unroll
    for (int k = 0; k < 4; ++k) {
      fa[k] = bf2f(g[k]);
      fb[k] = bf2f(g[k] >> 16);
    }
    const float ua0 = kNorm * (fa[0] + fa[2]), ua1 = kNorm * (fa[0] - fa[2]);
    const float ub0 = kNorm * (fb[0] + fb[2]), ub1 = kNorm * (fb[0] - fb[2]);
    t32[swzc(0, tid)] = pk2(kNorm * (ua0 + fa[1]), kNorm * (ub0 + fb[1]));
    t32[swzc(64, tid)] = pk2(kNorm * (ua0 - fa[1]), kNorm * (ub0 - fb[1]));
    t32[swzc(128, tid)] = pk2(kNorm * (ua1 + fa[3]), kNorm * (ub1 + fb[3]));
    t32[swzc(192, tid)] = pk2(kNorm * (ua1 - fa[3]), kNorm * (ub1 - fb[3]));
  }
  __syncthreads();

  // ---- inverse S2: levels 6,5,4 ----
  if (tid < 128) {
    const int cd = tid & 31;
    const int h0 = (tid >> 5) << 6;
    unsigned int g[8];
#pragma unroll
    for (int k = 0; k < 8; ++k) g[k] = t32[swzc(h0 + (k << 3), cd)];
    float fa[8], fb[8], oa[8], ob[8];
#pragma unroll
    for (int k = 0; k < 8; ++k) {
      fa[k] = bf2f(g[k]);
      fb[k] = bf2f(g[k] >> 16);
    }
    ilift3f(fa, oa);
    ilift3f(fb, ob);
#pragma unroll
    for (int k = 0; k < 8; ++k)
      t32[swzc(h0 + (k << 3), cd)] = pk2(oa[k], ob[k]);
  }
  __syncthreads();

  // ---- inverse S1: levels 3,2,1 in registers + global store ----
#pragma unroll
  for (int it = 0; it < 4; ++it) {
    const int h0 = (o8 << 3) + (it << 6);
    unsigned int g[8];
#pragma unroll
    for (int j = 0; j < 8; ++j) g[j] = t32[swzc(h0 + j, cdw)];
    float fa[8], fb[8], oa[8], ob[8];
#pragma unroll
    for (int j = 0; j < 8; ++j) {
      fa[j] = bf2f(g[j]);
      fb[j] = bf2f(g[j] >> 16);
    }
    ilift3f(fa, oa);
    ilift3f(fb, ob);
    ushort8 sA, sB;
#pragma unroll
    for (int j = 0; j < 8; ++j) {
      sA[j] = f2bf(oa[j]);
      sB[j] = f2bf(ob[j]);
    }
    *reinterpret_cast<ushort8*>(base + ((size_t)c0 << 16) + h0) = sA;
    *reinterpret_cast<ushort8*>(base + ((size_t)(c0 + 1) << 16) + h0) = sB;
  }
}

// ---------------- Kernel 3: inverse Haar along W (packed h-pairs) -> y ------
__global__ __launch_bounds__(256) void k_invW(const unsigned short* __restrict__ at,
                                              float* __restrict__ y) {
  __shared__ unsigned int t[16][260];  // [hd][w in-place] packed h-pairs
  const int blk = blockIdx.x;          // img*8 + htile
  const int img = blk >> 3;
  const int h0 = (blk & 7) << 5;
  const int tid = threadIdx.x;

  // ---- gather: pure dword copy (ws already bf16 h-pairs) ----
  const unsigned short* __restrict__ basep = at + ((size_t)img << 16) + h0;
#pragma unroll
  for (int k = 0; k < 4; ++k) {
    const int idx = (k << 8) + tid;
    const int wp = idx >> 2;
    const int hq = (idx & 3) << 2;
    const int wr = ip2ref(wp);
    const uint4v qv = *reinterpret_cast<const uint4v*>(
        basep + ((size_t)wr << 8) + (hq << 1));
    t[hq][wp] = qv[0];
    t[hq + 1][wp] = qv[1];
    t[hq + 2][wp] = qv[2];
    t[hq + 3][wp] = qv[3];
  }
  __syncthreads();

  // ---- inverse S3: levels 8,7 on {0,64,128,192} ----
  if (tid < 16) {
    const unsigned d0 = t[tid][0], d1 = t[tid][64];
    const unsigned d2 = t[tid][128], d3 = t[tid][192];
    const float e0 = bf2f(d0), e1 = bf2f(d1), e2 = bf2f(d2), e3 = bf2f(d3);
    const float p0 = bf2f(d0 >> 16), p1 = bf2f(d1 >> 16);
    const float p2 = bf2f(d2 >> 16), p3 = bf2f(d3 >> 16);
    const float ue0 = kNorm * (e0 + e2), ue1 = kNorm * (e0 - e2);
    const float uo0 = kNorm * (p0 + p2), uo1 = kNorm * (p0 - p2);
    t[tid][0] = pk2(kNorm * (ue0 + e1), kNorm * (uo0 + p1));
    t[tid][64] = pk2(kNorm * (ue0 - e1), kNorm * (uo0 - p1));
    t[tid][128] = pk2(kNorm * (ue1 + e3), kNorm * (uo1 + p3));
    t[tid][192] = pk2(kNorm * (ue1 - e3), kNorm * (uo1 - p3));
  }
  __syncthreads();

  // ---- inverse S2: levels 6,5,4 on stride-8 positions (staggered) ----
  if (tid < 64) {
    const int hd2 = tid & 15;
    const int q = tid >> 4;
    const int wq = q << 6;
    unsigned gd[8];
#pragma unroll
    for (int k0 = 0; k0 < 8; ++k0) {
      const int k = (k0 + (q << 1)) & 7;
      gd[k] = t[hd2][wq + (k << 3)];
    }
    float fe[8], fo[8], oe[8], oo[8];
#pragma unroll
    for (int k = 0; k < 8; ++k) {
      fe[k] = bf2f(gd[k]);
      fo[k] = bf2f(gd[k] >> 16);
    }
    ilift3f(fe, oe);
    ilift3f(fo, oo);
#pragma unroll
    for (int k0 = 0; k0 < 8; ++k0) {
      const int k = (k0 + (q << 1)) & 7;
      t[hd2][wq + (k << 3)] = pk2(oe[k], oo[k]);
    }
  }
  __syncthreads();

  // ---- inverse S1: levels 3,2,1 in registers, y store (rows 2hd, 2hd+1) ----
  const int g = tid & 7;
  const int hd = (tid >> 3) & 15;
  const int half = tid >> 7;
  float* __restrict__ yr0 =
      y + ((size_t)img << 16) + ((size_t)h0 << 8) + (hd << 9);
  float* __restrict__ yr1 = yr0 + 256;
#pragma unroll
  for (int it = 0; it < 2; ++it) {
    const int w0 = (g + (half << 3) + (it << 4)) << 3;
    const uint4v qa = *reinterpret_cast<const uint4v*>(&t[hd][w0]);
    const uint4v qb = *reinterpret_cast<const uint4v*>(&t[hd][w0 + 4]);
    float fe[8], fo[8], oe[8], oo[8];
#pragma unroll
    for (int j = 0; j < 4; ++j) {
      fe[j] = bf2f(qa[j]);
      fo[j] = bf2f(qa[j] >> 16);
      fe[4 + j] = bf2f(qb[j]);
      fo[4 + j] = bf2f(qb[j] >> 16);
    }
    ilift3f(fe, oe);
    ilift3f(fo, oo);
    float4 ya0 = {oe[0], oe[1], oe[2], oe[3]};
    float4 ya1 = {oe[4], oe[5], oe[6], oe[7]};
    float4 yb0 = {oo[0], oo[1], oo[2], oo[3]};
    float4 yb1 = {oo[4], oo[5], oo[6], oo[7]};
    *reinterpret_cast<float4*>(yr0 + w0) = ya0;
    *reinterpret_cast<float4*>(yr0 + w0 + 4) = ya1;
    *reinterpret_cast<float4*>(yr1 + w0) = yb0;
    *reinterpret_cast<float4*>(yr1 + w0 + 4) = yb1;
  }
}

}  // namespace

extern "C" void kernel_launch(void* const* d_in, const int* in_sizes, int n_in,
                              void* d_out, int out_size, void* d_ws, size_t ws_size,
                              hipStream_t stream) {
  (void)in_sizes; (void)n_in; (void)out_size; (void)ws_size;
  const float* x  = (const float*)d_in[0];
  const float* vv = (const float*)d_in[1];
  const float* cw = (const float*)d_in[2];
  const float* tt = (const float*)d_in[3];
  float* y = (float*)d_out;
  unsigned short* ws = (unsigned short*)d_ws;      // 128 MiB bf16 slab
  unsigned short* wb = ws + ((size_t)64 << 20);    // bf16 weights (16 KiB)
  unsigned int* vpk = (unsigned int*)(ws + ((size_t)64 << 20) + 16384);
  unsigned int* tpk = vpk + 65536;                 // 256 KiB each

  k_prep<<<256, 256, 0, stream>>>(cw, vv, tt, wb, vpk, tpk);
  k_fwdW<<<8192, 256, 0, stream>>>(x, ws);
  k_mid <<<4096, 256, 0, stream>>>(ws, wb, vpk, tpk);
  k_invW<<<8192, 256, 0, stream>>>(ws, y);
}

// Round 15
// 318.267 us; speedup vs baseline: 1.0171x; 1.0166x over previous
//
#include <hip/hip_runtime.h>
#include <hip/hip_bf16.h>

// Problem: B=16, C=64, H=256, W=256, P=2
// y = haar2d_inv( sum_p softthr( (haar2d(x)*v_p) @ w_p^T, tau_p ) ) + x
// Residual folded in wavelet domain: y = invHaar2d(acc + Haar2d(x)).
//
// ws: bf16 (b,c,wref,h) slab (128 MiB) + bf16 weights + packed/permuted v,tau.
//   k_prep : conv_w->bf16; v,tau -> bf16x2 packed, [w][h_inplace] layout
//   k_fwdW : x(f32) -> Hw(x), packed h-pair LDS tile, dword transposed store.
//   k_mid  : per (b,w) slab: staged Haar-H fwd -> MFMA mix (+F residual) ->
//            staged inverse -> store. GEMM restructured: Bf shrunk to
//            Bf[2][4] (32 regs), reloaded per (mt,op) from global (16 KiB
//            weights = L1-hot). Rounds 5-14 showed the persistent Bf[4][4]
//            (64 regs) was parked in AGPRs -> arch+agpr ~172 -> 2 waves/SIMD
//            (or spills when capped). Peak live now ~80-100 -> 4 blk/CU
//            reachable at launch_bounds(256,3) without forcing.
//            Tripwire: k_mid WRITE_SIZE must be 131072 KB (no spill).
//   k_invW : dword gather -> staged inverse lifting -> y.

namespace {

constexpr float kNorm = 0.70710678118654752440f;

typedef __attribute__((ext_vector_type(8))) short short8;
typedef __attribute__((ext_vector_type(4))) float f32x4;
typedef __attribute__((ext_vector_type(8))) unsigned short ushort8;
typedef __attribute__((ext_vector_type(4))) unsigned int uint4v;

// in-place lifting position -> reference subband position (n=256, 8 levels)
__device__ __forceinline__ int ip2ref(int p) {
  if (p == 0) return 0;
  const int j = __builtin_ctz(p) + 1;
  return (256 >> j) + (p >> j);
}
// reference subband position -> in-place lifting position
__device__ __forceinline__ int ref2ip(int r) {
  if (r == 0) return 0;
  const int tb = 31 - __builtin_clz(r);
  const int j = 8 - tb;
  return ((r - (1 << tb)) << j) | (1 << (j - 1));
}

__device__ __forceinline__ unsigned short f2bf(float f) {  // f32->bf16 RN
  unsigned int u = __float_as_uint(f);
  u += 0x7FFFu + ((u >> 16) & 1u);
  return (unsigned short)(u >> 16);
}
__device__ __forceinline__ float bf2f(unsigned int u) {
  return __uint_as_float((u & 0xFFFFu) << 16);
}
__device__ __forceinline__ unsigned pk2(float lo, float hi) {
  return (unsigned)f2bf(lo) | ((unsigned)f2bf(hi) << 16);
}

// 3-level forward Haar lifting on 8 values (in-place position convention)
__device__ __forceinline__ void lift3f(const float f[8], float o[8]) {
  const float a0 = kNorm * (f[0] + f[1]), d10 = kNorm * (f[0] - f[1]);
  const float a1 = kNorm * (f[2] + f[3]), d11 = kNorm * (f[2] - f[3]);
  const float a2 = kNorm * (f[4] + f[5]), d12 = kNorm * (f[4] - f[5]);
  const float a3 = kNorm * (f[6] + f[7]), d13 = kNorm * (f[6] - f[7]);
  const float b0 = kNorm * (a0 + a1), d20 = kNorm * (a0 - a1);
  const float b1 = kNorm * (a2 + a3), d21 = kNorm * (a2 - a3);
  o[0] = kNorm * (b0 + b1);
  o[4] = kNorm * (b0 - b1);
  o[2] = d20; o[6] = d21;
  o[1] = d10; o[3] = d11; o[5] = d12; o[7] = d13;
}
// inverse of lift3f
__device__ __forceinline__ void ilift3f(const float f[8], float o[8]) {
  const float b0 = kNorm * (f[0] + f[4]), b1 = kNorm * (f[0] - f[4]);
  const float a0 = kNorm * (b0 + f[2]), a1 = kNorm * (b0 - f[2]);
  const float a2 = kNorm * (b1 + f[6]), a3 = kNorm * (b1 - f[6]);
  o[0] = kNorm * (a0 + f[1]); o[1] = kNorm * (a0 - f[1]);
  o[2] = kNorm * (a1 + f[3]); o[3] = kNorm * (a1 - f[3]);
  o[4] = kNorm * (a2 + f[5]); o[5] = kNorm * (a2 - f[5]);
  o[6] = kNorm * (a3 + f[7]); o[7] = kNorm * (a3 - f[7]);
}

// ---------------- Kernel 0: weights -> bf16; v,tau -> packed/permuted -------
__global__ __launch_bounds__(256) void k_prep(const float* __restrict__ cw,
                                              const float* __restrict__ vv,
                                              const float* __restrict__ tt,
                                              unsigned short* __restrict__ wb,
                                              unsigned int* __restrict__ vpk,
                                              unsigned int* __restrict__ tpk) {
  const int idx = blockIdx.x * 256 + threadIdx.x;  // 65536 = 256 w x 256 hp
  if (idx < 8192) wb[idx] = f2bf(cw[idx]);
  const int w = idx >> 8;
  const int hp = idx & 255;                 // in-place h position
  const int off = (ip2ref(hp) << 8) + w;    // reference coord
  vpk[idx] = pk2(vv[off], vv[65536 + off]);
  tpk[idx] = pk2(tt[off], tt[65536 + off]);
}

// ---------------- Kernel 1: forward Haar along W (packed h-pairs) -----------
__global__ __launch_bounds__(256) void k_fwdW(const float* __restrict__ x,
                                              unsigned short* __restrict__ xt) {
  __shared__ unsigned int t[16][260];  // [hd][w] packed (h=2hd lo, 2hd+1 hi)
  const int blk = blockIdx.x;          // img*8 + htile
  const int img = blk >> 3;            // b*64 + c
  const int h0 = (blk & 7) << 5;
  const int tid = threadIdx.x;

  const float* __restrict__ src = x + ((size_t)img << 16) + ((size_t)h0 << 8);
  const int g = tid & 7;
  const int hd = (tid >> 3) & 15;
  const int half = tid >> 7;

  // ---- S1: levels 1-3 in registers, rows 2hd & 2hd+1, b128 LDS writes ----
  const float* __restrict__ r0 = src + (hd << 9);
  const float* __restrict__ r1 = r0 + 256;
#pragma unroll
  for (int it = 0; it < 2; ++it) {
    const int w0 = (g + (half << 3) + (it << 4)) << 3;
    const float4 a0 = *reinterpret_cast<const float4*>(r0 + w0);
    const float4 a1 = *reinterpret_cast<const float4*>(r0 + w0 + 4);
    const float4 b0 = *reinterpret_cast<const float4*>(r1 + w0);
    const float4 b1 = *reinterpret_cast<const float4*>(r1 + w0 + 4);
    float fe[8] = {a0.x, a0.y, a0.z, a0.w, a1.x, a1.y, a1.z, a1.w};
    float fo[8] = {b0.x, b0.y, b0.z, b0.w, b1.x, b1.y, b1.z, b1.w};
    float oe[8], oo[8];
    lift3f(fe, oe);
    lift3f(fo, oo);
    uint4v q0 = {pk2(oe[0], oo[0]), pk2(oe[1], oo[1]),
                 pk2(oe[2], oo[2]), pk2(oe[3], oo[3])};
    uint4v q1 = {pk2(oe[4], oo[4]), pk2(oe[5], oo[5]),
                 pk2(oe[6], oo[6]), pk2(oe[7], oo[7])};
    *reinterpret_cast<uint4v*>(&t[hd][w0]) = q0;
    *reinterpret_cast<uint4v*>(&t[hd][w0 + 4]) = q1;
  }
  __syncthreads();

  // ---- S2: levels 4-6 on stride-8 positions (2q-staggered k order) ----
  if (tid < 64) {
    const int hd2 = tid & 15;
    const int q = tid >> 4;  // 0..3
    const int wq = q << 6;
    unsigned gd[8];
#pragma unroll
    for (int k0 = 0; k0 < 8; ++k0) {
      const int k = (k0 + (q << 1)) & 7;
      gd[k] = t[hd2][wq + (k << 3)];
    }
    float fe[8], fo[8], oe[8], oo[8];
#pragma unroll
    for (int k = 0; k < 8; ++k) {
      fe[k] = bf2f(gd[k]);
      fo[k] = bf2f(gd[k] >> 16);
    }
    lift3f(fe, oe);
    lift3f(fo, oo);
#pragma unroll
    for (int k0 = 0; k0 < 8; ++k0) {
      const int k = (k0 + (q << 1)) & 7;
      t[hd2][wq + (k << 3)] = pk2(oe[k], oo[k]);
    }
  }
  __syncthreads();

  // ---- S3: levels 7-8 on {0,64,128,192} ----
  if (tid < 16) {
    const unsigned d0 = t[tid][0], d1 = t[tid][64];
    const unsigned d2 = t[tid][128], d3 = t[tid][192];
    const float e0 = bf2f(d0), e1 = bf2f(d1), e2 = bf2f(d2), e3 = bf2f(d3);
    const float p0 = bf2f(d0 >> 16), p1 = bf2f(d1 >> 16);
    const float p2 = bf2f(d2 >> 16), p3 = bf2f(d3 >> 16);
    const float ae0 = kNorm * (e0 + e1), de0 = kNorm * (e0 - e1);
    const float ae1 = kNorm * (e2 + e3), de1 = kNorm * (e2 - e3);
    const float ao0 = kNorm * (p0 + p1), do0 = kNorm * (p0 - p1);
    const float ao1 = kNorm * (p2 + p3), do1 = kNorm * (p2 - p3);
    t[tid][0] = pk2(kNorm * (ae0 + ae1), kNorm * (ao0 + ao1));
    t[tid][64] = pk2(de0, do0);
    t[tid][128] = pk2(kNorm * (ae0 - ae1), kNorm * (ao0 - ao1));
    t[tid][192] = pk2(de1, do1);
  }
  __syncthreads();

  // ---- transposed+permuted store: pure dword copy (already bf16 pairs) ----
  unsigned short* __restrict__ dst = xt + ((size_t)img << 16) + h0;
#pragma unroll
  for (int k = 0; k < 4; ++k) {
    const int idx = (k << 8) + tid;
    const int wp = idx >> 2;          // in-place w
    const int hq = (idx & 3) << 2;    // dword base: 0,4,8,12 (h = 2hq..2hq+7)
    const int wr = ip2ref(wp);
    uint4v qv = {t[hq][wp], t[hq + 1][wp], t[hq + 2][wp], t[hq + 3][wp]};
    *reinterpret_cast<uint4v*>(dst + ((size_t)wr << 8) + (hq << 1)) = qv;
  }
}

// ---------------- Kernel 2: staged Haar-H + MFMA mix (h-major packed LDS) ---
// tile dword (h, cdw): dwidx = h*32 + ((cdw + 4*(h&7) + 8*((h>>3)&3)) & 31)
__device__ __forceinline__ int swzc(int h, int cdw) {
  return (h << 5) | ((cdw + ((h & 7) << 2) + (((h >> 3) & 3) << 3)) & 31);
}

__global__ __launch_bounds__(256, 3) void k_mid(
    unsigned short* __restrict__ ws, const unsigned short* __restrict__ wb,
    const unsigned int* __restrict__ vpk, const unsigned int* __restrict__ tpk) {
  __shared__ unsigned int t32[8192];  // 32 KiB: [h=256][cdw=32] swizzled
  __shared__ unsigned int vt[512];    // [0..255]=v packed, [256..511]=tau packed
  unsigned short* t16 = reinterpret_cast<unsigned short*>(t32);

  const int blk = blockIdx.x;  // b*256 + w
  const int b = blk >> 8;
  const int w = blk & 255;
  const int tid = threadIdx.x;

  unsigned short* __restrict__ base = ws + ((size_t)b << 22) + ((size_t)w << 8);

  // stage v/tau (coalesced; already ip2ref-permuted by k_prep)
  vt[tid] = vpk[(w << 8) + tid];
  vt[256 + tid] = tpk[(w << 8) + tid];

  // ---- S1: global->reg, fwd levels 1-3 in registers, write tile ----
  const int cdw = tid >> 3;  // 0..31 (channel pair)
  const int c0 = cdw << 1;
  const int o8 = tid & 7;
#pragma unroll
  for (int it = 0; it < 4; ++it) {
    const int h0 = (o8 << 3) + (it << 6);
    const ushort8 rA =
        *reinterpret_cast<const ushort8*>(base + ((size_t)c0 << 16) + h0);
    const ushort8 rB =
        *reinterpret_cast<const ushort8*>(base + ((size_t)(c0 + 1) << 16) + h0);
    float fa[8], fb[8], oa[8], ob[8];
#pragma unroll
    for (int j = 0; j < 8; ++j) {
      fa[j] = bf2f(rA[j]);
      fb[j] = bf2f(rB[j]);
    }
    lift3f(fa, oa);
    lift3f(fb, ob);
#pragma unroll
    for (int j = 0; j < 8; ++j) t32[swzc(h0 + j, cdw)] = pk2(oa[j], ob[j]);
  }
  __syncthreads();

  // ---- S2: fwd levels 4-6 (8 values @ stride 8), 128 threads ----
  if (tid < 128) {
    const int cd = tid & 31;
    const int h0 = (tid >> 5) << 6;
    unsigned int g[8];
#pragma unroll
    for (int k = 0; k < 8; ++k) g[k] = t32[swzc(h0 + (k << 3), cd)];
    float fa[8], fb[8], oa[8], ob[8];
#pragma unroll
    for (int k = 0; k < 8; ++k) {
      fa[k] = bf2f(g[k]);
      fb[k] = bf2f(g[k] >> 16);
    }
    lift3f(fa, oa);
    lift3f(fb, ob);
#pragma unroll
    for (int k = 0; k < 8; ++k)
      t32[swzc(h0 + (k << 3), cd)] = pk2(oa[k], ob[k]);
  }
  __syncthreads();

  // ---- S3: fwd levels 7-8 (4 values @ stride 64), 32 threads ----
  if (tid < 32) {
    unsigned int g[4];
#pragma unroll
    for (int k = 0; k < 4; ++k) g[k] = t32[swzc(k << 6, tid)];
    float fa[4], fb[4];
#pragma unroll
    for (int k = 0; k < 4; ++k) {
      fa[k] = bf2f(g[k]);
      fb[k] = bf2f(g[k] >> 16);
    }
    const float aa0 = kNorm * (fa[0] + fa[1]), da0 = kNorm * (fa[0] - fa[1]);
    const float aa1 = kNorm * (fa[2] + fa[3]), da1 = kNorm * (fa[2] - fa[3]);
    const float ab0 = kNorm * (fb[0] + fb[1]), db0 = kNorm * (fb[0] - fb[1]);
    const float ab1 = kNorm * (fb[2] + fb[3]), db1 = kNorm * (fb[2] - fb[3]);
    t32[swzc(0, tid)] = pk2(kNorm * (aa0 + aa1), kNorm * (ab0 + ab1));
    t32[swzc(64, tid)] = pk2(da0, db0);
    t32[swzc(128, tid)] = pk2(kNorm * (aa0 - aa1), kNorm * (ab0 - ab1));
    t32[swzc(192, tid)] = pk2(da1, db1);
  }
  __syncthreads();

  // ---- GEMM + fused epilogue (acc + F residual), per-wave 64-row strip ----
  // mt OUTER (A-fragments + v/tau read first -> no in-place race), og-pair
  // INNER with Bf[2][4] (32 regs) reloaded per (mt,op). Weights are 16 KiB
  // -> L1-resident; keeps arch+agpr live set ~<100 so HW can co-schedule
  // 4 blocks/CU at launch_bounds(256,3).
  const int l15 = tid & 15;
  const int l4 = (tid & 63) >> 4;
  const int strip = (tid >> 6) << 6;
#pragma unroll 1
  for (int mt = 0; mt < 4; ++mt) {
    const int hh = strip + (mt << 4) + l15;
    const short8 a0 =
        *reinterpret_cast<const short8*>(&t32[swzc(hh, l4 << 2)]);
    const short8 a1 =
        *reinterpret_cast<const short8*>(&t32[swzc(hh, 16 + (l4 << 2))]);
    const int hb = strip + (mt << 4) + (l4 << 2);
    const uint4v vq = *reinterpret_cast<const uint4v*>(&vt[hb]);
    const uint4v tq = *reinterpret_cast<const uint4v*>(&vt[256 + hb]);
#pragma unroll 1
    for (int op = 0; op < 2; ++op) {
      short8 Bf[2][4];
#pragma unroll
      for (int g2 = 0; g2 < 2; ++g2) {
        const int o = (((op << 1) + g2) << 4) + l15;
        const unsigned short* wr0 = wb + (o << 6) + (l4 << 3);         // p=0
        const unsigned short* wr1 = wb + 4096 + (o << 6) + (l4 << 3);  // p=1
        Bf[g2][0] = *reinterpret_cast<const short8*>(wr0);
        Bf[g2][1] = *reinterpret_cast<const short8*>(wr0 + 32);
        Bf[g2][2] = *reinterpret_cast<const short8*>(wr1);
        Bf[g2][3] = *reinterpret_cast<const short8*>(wr1 + 32);
      }
#pragma unroll
      for (int g2 = 0; g2 < 2; ++g2) {
        const int o = (((op << 1) + g2) << 4) + l15;
        f32x4 accL = {0.f, 0.f, 0.f, 0.f};
        f32x4 accH = {0.f, 0.f, 0.f, 0.f};
        accL = __builtin_amdgcn_mfma_f32_16x16x32_bf16(a0, Bf[g2][0], accL, 0, 0, 0);
        accH = __builtin_amdgcn_mfma_f32_16x16x32_bf16(a0, Bf[g2][2], accH, 0, 0, 0);
        accL = __builtin_amdgcn_mfma_f32_16x16x32_bf16(a1, Bf[g2][1], accL, 0, 0, 0);
        accH = __builtin_amdgcn_mfma_f32_16x16x32_bf16(a1, Bf[g2][3], accH, 0, 0, 0);
#pragma unroll
        for (int r = 0; r < 4; ++r) {
          const float v0 = bf2f(vq[r]), v1 = bf2f(vq[r] >> 16);
          const float t0 = bf2f(tq[r]), t1 = bf2f(tq[r] >> 16);
          const float g0 = accL[r] * v0;
          const float g1 = accH[r] * v1;
          float rr = 0.f;
          const float q0 = fabsf(g0) - t0;
          if (q0 > 0.f) rr += copysignf(q0, g0);
          const float q1 = fabsf(g1) - t1;
          if (q1 > 0.f) rr += copysignf(q1, g1);
          const int idx16 = (swzc(hb + r, o >> 1) << 1) | (o & 1);
          const float Fv = bf2f(t16[idx16]);  // residual in wavelet domain
          t16[idx16] = f2bf(rr + Fv);
        }
      }
    }
  }
  __syncthreads();

  // ---- inverse S3: levels 8,7 ----
  if (tid < 32) {
    unsigned int g[4];
#pragma unroll
    for (int k = 0; k < 4; ++k) g[k] = t32[swzc(k << 6, tid)];
    float fa[4], fb[4];
#pragma unroll
    for (int k = 0; k < 4; ++k) {
      fa[k] = bf2f(g[k]);
      fb[k] = bf2f(g[k] >> 16);
    }
    const float ua0 = kNorm * (fa[0] + fa[2]), ua1 = kNorm * (fa[0] - fa[2]);
    const float ub0 = kNorm * (fb[0] + fb[2]), ub1 = kNorm * (fb[0] - fb[2]);
    t32[swzc(0, tid)] = pk2(kNorm * (ua0 + fa[1]), kNorm * (ub0 + fb[1]));
    t32[swzc(64, tid)] = pk2(kNorm * (ua0 - fa[1]), kNorm * (ub0 - fb[1]));
    t32[swzc(128, tid)] = pk2(kNorm * (ua1 + fa[3]), kNorm * (ub1 + fb[3]));
    t32[swzc(192, tid)] = pk2(kNorm * (ua1 - fa[3]), kNorm * (ub1 - fb[3]));
  }
  __syncthreads();

  // ---- inverse S2: levels 6,5,4 ----
  if (tid < 128) {
    const int cd = tid & 31;
    const int h0 = (tid >> 5) << 6;
    unsigned int g[8];
#pragma unroll
    for (int k = 0; k < 8; ++k) g[k] = t32[swzc(h0 + (k << 3), cd)];
    float fa[8], fb[8], oa[8], ob[8];
#pragma unroll
    for (int k = 0; k < 8; ++k) {
      fa[k] = bf2f(g[k]);
      fb[k] = bf2f(g[k] >> 16);
    }
    ilift3f(fa, oa);
    ilift3f(fb, ob);
#pragma unroll
    for (int k = 0; k < 8; ++k)
      t32[swzc(h0 + (k << 3), cd)] = pk2(oa[k], ob[k]);
  }
  __syncthreads();

  // ---- inverse S1: levels 3,2,1 in registers + global store ----
#pragma unroll
  for (int it = 0; it < 4; ++it) {
    const int h0 = (o8 << 3) + (it << 6);
    unsigned int g[8];
#pragma unroll
    for (int j = 0; j < 8; ++j) g[j] = t32[swzc(h0 + j, cdw)];
    float fa[8], fb[8], oa[8], ob[8];
#pragma unroll
    for (int j = 0; j < 8; ++j) {
      fa[j] = bf2f(g[j]);
      fb[j] = bf2f(g[j] >> 16);
    }
    ilift3f(fa, oa);
    ilift3f(fb, ob);
    ushort8 sA, sB;
#pragma unroll
    for (int j = 0; j < 8; ++j) {
      sA[j] = f2bf(oa[j]);
      sB[j] = f2bf(ob[j]);
    }
    *reinterpret_cast<ushort8*>(base + ((size_t)c0 << 16) + h0) = sA;
    *reinterpret_cast<ushort8*>(base + ((size_t)(c0 + 1) << 16) + h0) = sB;
  }
}

// ---------------- Kernel 3: inverse Haar along W (packed h-pairs) -> y ------
__global__ __launch_bounds__(256) void k_invW(const unsigned short* __restrict__ at,
                                              float* __restrict__ y) {
  __shared__ unsigned int t[16][260];  // [hd][w in-place] packed h-pairs
  const int blk = blockIdx.x;          // img*8 + htile
  const int img = blk >> 3;
  const int h0 = (blk & 7) << 5;
  const int tid = threadIdx.x;

  // ---- gather: pure dword copy (ws already bf16 h-pairs) ----
  const unsigned short* __restrict__ basep = at + ((size_t)img << 16) + h0;
#pragma unroll
  for (int k = 0; k < 4; ++k) {
    const int idx = (k << 8) + tid;
    const int wp = idx >> 2;
    const int hq = (idx & 3) << 2;
    const int wr = ip2ref(wp);
    const uint4v qv = *reinterpret_cast<const uint4v*>(
        basep + ((size_t)wr << 8) + (hq << 1));
    t[hq][wp] = qv[0];
    t[hq + 1][wp] = qv[1];
    t[hq + 2][wp] = qv[2];
    t[hq + 3][wp] = qv[3];
  }
  __syncthreads();

  // ---- inverse S3: levels 8,7 on {0,64,128,192} ----
  if (tid < 16) {
    const unsigned d0 = t[tid][0], d1 = t[tid][64];
    const unsigned d2 = t[tid][128], d3 = t[tid][192];
    const float e0 = bf2f(d0), e1 = bf2f(d1), e2 = bf2f(d2), e3 = bf2f(d3);
    const float p0 = bf2f(d0 >> 16), p1 = bf2f(d1 >> 16);
    const float p2 = bf2f(d2 >> 16), p3 = bf2f(d3 >> 16);
    const float ue0 = kNorm * (e0 + e2), ue1 = kNorm * (e0 - e2);
    const float uo0 = kNorm * (p0 + p2), uo1 = kNorm * (p0 - p2);
    t[tid][0] = pk2(kNorm * (ue0 + e1), kNorm * (uo0 + p1));
    t[tid][64] = pk2(kNorm * (ue0 - e1), kNorm * (uo0 - p1));
    t[tid][128] = pk2(kNorm * (ue1 + e3), kNorm * (uo1 + p3));
    t[tid][192] = pk2(kNorm * (ue1 - e3), kNorm * (uo1 - p3));
  }
  __syncthreads();

  // ---- inverse S2: levels 6,5,4 on stride-8 positions (staggered) ----
  if (tid < 64) {
    const int hd2 = tid & 15;
    const int q = tid >> 4;
    const int wq = q << 6;
    unsigned gd[8];
#pragma unroll
    for (int k0 = 0; k0 < 8; ++k0) {
      const int k = (k0 + (q << 1)) & 7;
      gd[k] = t[hd2][wq + (k << 3)];
    }
    float fe[8], fo[8], oe[8], oo[8];
#pragma unroll
    for (int k = 0; k < 8; ++k) {
      fe[k] = bf2f(gd[k]);
      fo[k] = bf2f(gd[k] >> 16);
    }
    ilift3f(fe, oe);
    ilift3f(fo, oo);
#pragma unroll
    for (int k0 = 0; k0 < 8; ++k0) {
      const int k = (k0 + (q << 1)) & 7;
      t[hd2][wq + (k << 3)] = pk2(oe[k], oo[k]);
    }
  }
  __syncthreads();

  // ---- inverse S1: levels 3,2,1 in registers, y store (rows 2hd, 2hd+1) ----
  const int g = tid & 7;
  const int hd = (tid >> 3) & 15;
  const int half = tid >> 7;
  float* __restrict__ yr0 =
      y + ((size_t)img << 16) + ((size_t)h0 << 8) + (hd << 9);
  float* __restrict__ yr1 = yr0 + 256;
#pragma unroll
  for (int it = 0; it < 2; ++it) {
    const int w0 = (g + (half << 3) + (it << 4)) << 3;
    const uint4v qa = *reinterpret_cast<const uint4v*>(&t[hd][w0]);
    const uint4v qb = *reinterpret_cast<const uint4v*>(&t[hd][w0 + 4]);
    float fe[8], fo[8], oe[8], oo[8];
#pragma unroll
    for (int j = 0; j < 4; ++j) {
      fe[j] = bf2f(qa[j]);
      fo[j] = bf2f(qa[j] >> 16);
      fe[4 + j] = bf2f(qb[j]);
      fo[4 + j] = bf2f(qb[j] >> 16);
    }
    ilift3f(fe, oe);
    ilift3f(fo, oo);
    float4 ya0 = {oe[0], oe[1], oe[2], oe[3]};
    float4 ya1 = {oe[4], oe[5], oe[6], oe[7]};
    float4 yb0 = {oo[0], oo[1], oo[2], oo[3]};
    float4 yb1 = {oo[4], oo[5], oo[6], oo[7]};
    *reinterpret_cast<float4*>(yr0 + w0) = ya0;
    *reinterpret_cast<float4*>(yr0 + w0 + 4) = ya1;
    *reinterpret_cast<float4*>(yr1 + w0) = yb0;
    *reinterpret_cast<float4*>(yr1 + w0 + 4) = yb1;
  }
}

}  // namespace

extern "C" void kernel_launch(void* const* d_in, const int* in_sizes, int n_in,
                              void* d_out, int out_size, void* d_ws, size_t ws_size,
                              hipStream_t stream) {
  (void)in_sizes; (void)n_in; (void)out_size; (void)ws_size;
  const float* x  = (const float*)d_in[0];
  const float* vv = (const float*)d_in[1];
  const float* cw = (const float*)d_in[2];
  const float* tt = (const float*)d_in[3];
  float* y = (float*)d_out;
  unsigned short* ws = (unsigned short*)d_ws;      // 128 MiB bf16 slab
  unsigned short* wb = ws + ((size_t)64 << 20);    // bf16 weights (16 KiB)
  unsigned int* vpk = (unsigned int*)(ws + ((size_t)64 << 20) + 16384);
  unsigned int* tpk = vpk + 65536;                 // 256 KiB each

  k_prep<<<256, 256, 0, stream>>>(cw, vv, tt, wb, vpk, tpk);
  k_fwdW<<<8192, 256, 0, stream>>>(x, ws);
  k_mid <<<4096, 256, 0, stream>>>(ws, wb, vpk, tpk);
  k_invW<<<8192, 256, 0, stream>>>(ws, y);
}

// Round 16
// 262.516 us; speedup vs baseline: 1.2331x; 1.2124x over previous
//
#include <hip/hip_runtime.h>
#include <hip/hip_bf16.h>

// Problem: B=16, C=64, H=256, W=256, P=2
// y = haar2d_inv( sum_p softthr( (haar2d(x)*v_p) @ w_p^T, tau_p ) ) + x
// Residual folded in wavelet domain: y = invHaar2d(acc + Haar2d(x)).
//
// FINAL (round-12 config, best measured 261.6-262.7 us):
//   - 3 passes x 1024 MiB bf16 workspace traffic (algorithmic minimum),
//     floor ~163 us; measured ~262 us.
//   - k_mid: launch_bounds(256,3), Bf[4][4] preloaded ONCE before S1
//     (AGPR-parked). Rounds 13-15 proved every alternative is worse:
//     (256,4) spills ~180 MB scratch (r13), sched_barrier doesn't stop the
//     hoist (r14), per-(mt,op) reload serializes on L1 latency (r15).
//
// ws: bf16 (b,c,wref,h) slab (128 MiB) + bf16 weights + packed/permuted v,tau.
//   k_prep : conv_w->bf16; v,tau -> bf16x2 packed, [w][h_inplace] layout
//   k_fwdW : x(f32) -> Hw(x), packed h-pair LDS tile, dword transposed store.
//   k_mid  : per (b,w) slab: staged Haar-H fwd -> MFMA mix (+F residual) ->
//            staged inverse -> store.
//   k_invW : dword gather -> staged inverse lifting -> y.

namespace {

constexpr float kNorm = 0.70710678118654752440f;

typedef __attribute__((ext_vector_type(8))) short short8;
typedef __attribute__((ext_vector_type(4))) float f32x4;
typedef __attribute__((ext_vector_type(8))) unsigned short ushort8;
typedef __attribute__((ext_vector_type(4))) unsigned int uint4v;

// in-place lifting position -> reference subband position (n=256, 8 levels)
__device__ __forceinline__ int ip2ref(int p) {
  if (p == 0) return 0;
  const int j = __builtin_ctz(p) + 1;
  return (256 >> j) + (p >> j);
}
// reference subband position -> in-place lifting position
__device__ __forceinline__ int ref2ip(int r) {
  if (r == 0) return 0;
  const int tb = 31 - __builtin_clz(r);
  const int j = 8 - tb;
  return ((r - (1 << tb)) << j) | (1 << (j - 1));
}

__device__ __forceinline__ unsigned short f2bf(float f) {  // f32->bf16 RN
  unsigned int u = __float_as_uint(f);
  u += 0x7FFFu + ((u >> 16) & 1u);
  return (unsigned short)(u >> 16);
}
__device__ __forceinline__ float bf2f(unsigned int u) {
  return __uint_as_float((u & 0xFFFFu) << 16);
}
__device__ __forceinline__ unsigned pk2(float lo, float hi) {
  return (unsigned)f2bf(lo) | ((unsigned)f2bf(hi) << 16);
}

// 3-level forward Haar lifting on 8 values (in-place position convention)
__device__ __forceinline__ void lift3f(const float f[8], float o[8]) {
  const float a0 = kNorm * (f[0] + f[1]), d10 = kNorm * (f[0] - f[1]);
  const float a1 = kNorm * (f[2] + f[3]), d11 = kNorm * (f[2] - f[3]);
  const float a2 = kNorm * (f[4] + f[5]), d12 = kNorm * (f[4] - f[5]);
  const float a3 = kNorm * (f[6] + f[7]), d13 = kNorm * (f[6] - f[7]);
  const float b0 = kNorm * (a0 + a1), d20 = kNorm * (a0 - a1);
  const float b1 = kNorm * (a2 + a3), d21 = kNorm * (a2 - a3);
  o[0] = kNorm * (b0 + b1);
  o[4] = kNorm * (b0 - b1);
  o[2] = d20; o[6] = d21;
  o[1] = d10; o[3] = d11; o[5] = d12; o[7] = d13;
}
// inverse of lift3f
__device__ __forceinline__ void ilift3f(const float f[8], float o[8]) {
  const float b0 = kNorm * (f[0] + f[4]), b1 = kNorm * (f[0] - f[4]);
  const float a0 = kNorm * (b0 + f[2]), a1 = kNorm * (b0 - f[2]);
  const float a2 = kNorm * (b1 + f[6]), a3 = kNorm * (b1 - f[6]);
  o[0] = kNorm * (a0 + f[1]); o[1] = kNorm * (a0 - f[1]);
  o[2] = kNorm * (a1 + f[3]); o[3] = kNorm * (a1 - f[3]);
  o[4] = kNorm * (a2 + f[5]); o[5] = kNorm * (a2 - f[5]);
  o[6] = kNorm * (a3 + f[7]); o[7] = kNorm * (a3 - f[7]);
}

// ---------------- Kernel 0: weights -> bf16; v,tau -> packed/permuted -------
__global__ __launch_bounds__(256) void k_prep(const float* __restrict__ cw,
                                              const float* __restrict__ vv,
                                              const float* __restrict__ tt,
                                              unsigned short* __restrict__ wb,
                                              unsigned int* __restrict__ vpk,
                                              unsigned int* __restrict__ tpk) {
  const int idx = blockIdx.x * 256 + threadIdx.x;  // 65536 = 256 w x 256 hp
  if (idx < 8192) wb[idx] = f2bf(cw[idx]);
  const int w = idx >> 8;
  const int hp = idx & 255;                 // in-place h position
  const int off = (ip2ref(hp) << 8) + w;    // reference coord
  vpk[idx] = pk2(vv[off], vv[65536 + off]);
  tpk[idx] = pk2(tt[off], tt[65536 + off]);
}

// ---------------- Kernel 1: forward Haar along W (packed h-pairs) -----------
__global__ __launch_bounds__(256) void k_fwdW(const float* __restrict__ x,
                                              unsigned short* __restrict__ xt) {
  __shared__ unsigned int t[16][260];  // [hd][w] packed (h=2hd lo, 2hd+1 hi)
  const int blk = blockIdx.x;          // img*8 + htile
  const int img = blk >> 3;            // b*64 + c
  const int h0 = (blk & 7) << 5;
  const int tid = threadIdx.x;

  const float* __restrict__ src = x + ((size_t)img << 16) + ((size_t)h0 << 8);
  const int g = tid & 7;
  const int hd = (tid >> 3) & 15;
  const int half = tid >> 7;

  // ---- S1: levels 1-3 in registers, rows 2hd & 2hd+1, b128 LDS writes ----
  const float* __restrict__ r0 = src + (hd << 9);
  const float* __restrict__ r1 = r0 + 256;
#pragma unroll
  for (int it = 0; it < 2; ++it) {
    const int w0 = (g + (half << 3) + (it << 4)) << 3;
    const float4 a0 = *reinterpret_cast<const float4*>(r0 + w0);
    const float4 a1 = *reinterpret_cast<const float4*>(r0 + w0 + 4);
    const float4 b0 = *reinterpret_cast<const float4*>(r1 + w0);
    const float4 b1 = *reinterpret_cast<const float4*>(r1 + w0 + 4);
    float fe[8] = {a0.x, a0.y, a0.z, a0.w, a1.x, a1.y, a1.z, a1.w};
    float fo[8] = {b0.x, b0.y, b0.z, b0.w, b1.x, b1.y, b1.z, b1.w};
    float oe[8], oo[8];
    lift3f(fe, oe);
    lift3f(fo, oo);
    uint4v q0 = {pk2(oe[0], oo[0]), pk2(oe[1], oo[1]),
                 pk2(oe[2], oo[2]), pk2(oe[3], oo[3])};
    uint4v q1 = {pk2(oe[4], oo[4]), pk2(oe[5], oo[5]),
                 pk2(oe[6], oo[6]), pk2(oe[7], oo[7])};
    *reinterpret_cast<uint4v*>(&t[hd][w0]) = q0;
    *reinterpret_cast<uint4v*>(&t[hd][w0 + 4]) = q1;
  }
  __syncthreads();

  // ---- S2: levels 4-6 on stride-8 positions (2q-staggered k order) ----
  if (tid < 64) {
    const int hd2 = tid & 15;
    const int q = tid >> 4;  // 0..3
    const int wq = q << 6;
    unsigned gd[8];
#pragma unroll
    for (int k0 = 0; k0 < 8; ++k0) {
      const int k = (k0 + (q << 1)) & 7;
      gd[k] = t[hd2][wq + (k << 3)];
    }
    float fe[8], fo[8], oe[8], oo[8];
#pragma unroll
    for (int k = 0; k < 8; ++k) {
      fe[k] = bf2f(gd[k]);
      fo[k] = bf2f(gd[k] >> 16);
    }
    lift3f(fe, oe);
    lift3f(fo, oo);
#pragma unroll
    for (int k0 = 0; k0 < 8; ++k0) {
      const int k = (k0 + (q << 1)) & 7;
      t[hd2][wq + (k << 3)] = pk2(oe[k], oo[k]);
    }
  }
  __syncthreads();

  // ---- S3: levels 7-8 on {0,64,128,192} ----
  if (tid < 16) {
    const unsigned d0 = t[tid][0], d1 = t[tid][64];
    const unsigned d2 = t[tid][128], d3 = t[tid][192];
    const float e0 = bf2f(d0), e1 = bf2f(d1), e2 = bf2f(d2), e3 = bf2f(d3);
    const float p0 = bf2f(d0 >> 16), p1 = bf2f(d1 >> 16);
    const float p2 = bf2f(d2 >> 16), p3 = bf2f(d3 >> 16);
    const float ae0 = kNorm * (e0 + e1), de0 = kNorm * (e0 - e1);
    const float ae1 = kNorm * (e2 + e3), de1 = kNorm * (e2 - e3);
    const float ao0 = kNorm * (p0 + p1), do0 = kNorm * (p0 - p1);
    const float ao1 = kNorm * (p2 + p3), do1 = kNorm * (p2 - p3);
    t[tid][0] = pk2(kNorm * (ae0 + ae1), kNorm * (ao0 + ao1));
    t[tid][64] = pk2(de0, do0);
    t[tid][128] = pk2(kNorm * (ae0 - ae1), kNorm * (ao0 - ao1));
    t[tid][192] = pk2(de1, do1);
  }
  __syncthreads();

  // ---- transposed+permuted store: pure dword copy (already bf16 pairs) ----
  unsigned short* __restrict__ dst = xt + ((size_t)img << 16) + h0;
#pragma unroll
  for (int k = 0; k < 4; ++k) {
    const int idx = (k << 8) + tid;
    const int wp = idx >> 2;          // in-place w
    const int hq = (idx & 3) << 2;    // dword base: 0,4,8,12 (h = 2hq..2hq+7)
    const int wr = ip2ref(wp);
    uint4v qv = {t[hq][wp], t[hq + 1][wp], t[hq + 2][wp], t[hq + 3][wp]};
    *reinterpret_cast<uint4v*>(dst + ((size_t)wr << 8) + (hq << 1)) = qv;
  }
}

// ---------------- Kernel 2: staged Haar-H + MFMA mix (h-major packed LDS) ---
// tile dword (h, cdw): dwidx = h*32 + ((cdw + 4*(h&7) + 8*((h>>3)&3)) & 31)
__device__ __forceinline__ int swzc(int h, int cdw) {
  return (h << 5) | ((cdw + ((h & 7) << 2) + (((h >> 3) & 3) << 3)) & 31);
}

__global__ __launch_bounds__(256, 3) void k_mid(
    unsigned short* __restrict__ ws, const unsigned short* __restrict__ wb,
    const unsigned int* __restrict__ vpk, const unsigned int* __restrict__ tpk) {
  __shared__ unsigned int t32[8192];  // 32 KiB: [h=256][cdw=32] swizzled
  __shared__ unsigned int vt[512];    // [0..255]=v packed, [256..511]=tau packed
  unsigned short* t16 = reinterpret_cast<unsigned short*>(t32);

  const int blk = blockIdx.x;  // b*256 + w
  const int b = blk >> 8;
  const int w = blk & 255;
  const int tid = threadIdx.x;

  unsigned short* __restrict__ base = ws + ((size_t)b << 22) + ((size_t)w << 8);

  // stage v/tau (coalesced; already ip2ref-permuted by k_prep)
  vt[tid] = vpk[(w << 8) + tid];
  vt[256 + tid] = tpk[(w << 8) + tid];

  // ---- B-fragment preload: mt-invariant, load ONCE (AGPR-parked by design;
  //      rounds 13-15 proved all alternatives are worse).
  const int l15 = tid & 15;
  const int l4 = (tid & 63) >> 4;
  short8 Bf[4][4];
#pragma unroll
  for (int og = 0; og < 4; ++og) {
    const int o = (og << 4) + l15;
    const unsigned short* wr0 = wb + (o << 6) + (l4 << 3);         // p=0
    const unsigned short* wr1 = wb + 4096 + (o << 6) + (l4 << 3);  // p=1
    Bf[og][0] = *reinterpret_cast<const short8*>(wr0);
    Bf[og][1] = *reinterpret_cast<const short8*>(wr0 + 32);
    Bf[og][2] = *reinterpret_cast<const short8*>(wr1);
    Bf[og][3] = *reinterpret_cast<const short8*>(wr1 + 32);
  }

  // ---- S1: global->reg, fwd levels 1-3 in registers, write tile ----
  const int cdw = tid >> 3;  // 0..31 (channel pair)
  const int c0 = cdw << 1;
  const int o8 = tid & 7;
#pragma unroll
  for (int it = 0; it < 4; ++it) {
    const int h0 = (o8 << 3) + (it << 6);
    const ushort8 rA =
        *reinterpret_cast<const ushort8*>(base + ((size_t)c0 << 16) + h0);
    const ushort8 rB =
        *reinterpret_cast<const ushort8*>(base + ((size_t)(c0 + 1) << 16) + h0);
    float fa[8], fb[8], oa[8], ob[8];
#pragma unroll
    for (int j = 0; j < 8; ++j) {
      fa[j] = bf2f(rA[j]);
      fb[j] = bf2f(rB[j]);
    }
    lift3f(fa, oa);
    lift3f(fb, ob);
#pragma unroll
    for (int j = 0; j < 8; ++j) t32[swzc(h0 + j, cdw)] = pk2(oa[j], ob[j]);
  }
  __syncthreads();

  // ---- S2: fwd levels 4-6 (8 values @ stride 8), 128 threads ----
  if (tid < 128) {
    const int cd = tid & 31;
    const int h0 = (tid >> 5) << 6;
    unsigned int g[8];
#pragma unroll
    for (int k = 0; k < 8; ++k) g[k] = t32[swzc(h0 + (k << 3), cd)];
    float fa[8], fb[8], oa[8], ob[8];
#pragma unroll
    for (int k = 0; k < 8; ++k) {
      fa[k] = bf2f(g[k]);
      fb[k] = bf2f(g[k] >> 16);
    }
    lift3f(fa, oa);
    lift3f(fb, ob);
#pragma unroll
    for (int k = 0; k < 8; ++k)
      t32[swzc(h0 + (k << 3), cd)] = pk2(oa[k], ob[k]);
  }
  __syncthreads();

  // ---- S3: fwd levels 7-8 (4 values @ stride 64), 32 threads ----
  if (tid < 32) {
    unsigned int g[4];
#pragma unroll
    for (int k = 0; k < 4; ++k) g[k] = t32[swzc(k << 6, tid)];
    float fa[4], fb[4];
#pragma unroll
    for (int k = 0; k < 4; ++k) {
      fa[k] = bf2f(g[k]);
      fb[k] = bf2f(g[k] >> 16);
    }
    const float aa0 = kNorm * (fa[0] + fa[1]), da0 = kNorm * (fa[0] - fa[1]);
    const float aa1 = kNorm * (fa[2] + fa[3]), da1 = kNorm * (fa[2] - fa[3]);
    const float ab0 = kNorm * (fb[0] + fb[1]), db0 = kNorm * (fb[0] - fb[1]);
    const float ab1 = kNorm * (fb[2] + fb[3]), db1 = kNorm * (fb[2] - fb[3]);
    t32[swzc(0, tid)] = pk2(kNorm * (aa0 + aa1), kNorm * (ab0 + ab1));
    t32[swzc(64, tid)] = pk2(da0, db0);
    t32[swzc(128, tid)] = pk2(kNorm * (aa0 - aa1), kNorm * (ab0 - ab1));
    t32[swzc(192, tid)] = pk2(da1, db1);
  }
  __syncthreads();

  // ---- GEMM + fused epilogue (acc + F residual), per-wave 64-row strip ----
  const int strip = (tid >> 6) << 6;
#pragma unroll 1
  for (int mt = 0; mt < 4; ++mt) {
    const int hh = strip + (mt << 4) + l15;
    const short8 a0 =
        *reinterpret_cast<const short8*>(&t32[swzc(hh, l4 << 2)]);
    const short8 a1 =
        *reinterpret_cast<const short8*>(&t32[swzc(hh, 16 + (l4 << 2))]);
    const int hb = strip + (mt << 4) + (l4 << 2);
    const uint4v vq = *reinterpret_cast<const uint4v*>(&vt[hb]);
    const uint4v tq = *reinterpret_cast<const uint4v*>(&vt[256 + hb]);
#pragma unroll
    for (int og = 0; og < 4; ++og) {
      const int o = (og << 4) + l15;
      f32x4 accL = {0.f, 0.f, 0.f, 0.f};
      f32x4 accH = {0.f, 0.f, 0.f, 0.f};
      accL = __builtin_amdgcn_mfma_f32_16x16x32_bf16(a0, Bf[og][0], accL, 0, 0, 0);
      accH = __builtin_amdgcn_mfma_f32_16x16x32_bf16(a0, Bf[og][2], accH, 0, 0, 0);
      accL = __builtin_amdgcn_mfma_f32_16x16x32_bf16(a1, Bf[og][1], accL, 0, 0, 0);
      accH = __builtin_amdgcn_mfma_f32_16x16x32_bf16(a1, Bf[og][3], accH, 0, 0, 0);
#pragma unroll
      for (int r = 0; r < 4; ++r) {
        const float v0 = bf2f(vq[r]), v1 = bf2f(vq[r] >> 16);
        const float t0 = bf2f(tq[r]), t1 = bf2f(tq[r] >> 16);
        const float g0 = accL[r] * v0;
        const float g1 = accH[r] * v1;
        float rr = 0.f;
        const float q0 = fabsf(g0) - t0;
        if (q0 > 0.f) rr += copysignf(q0, g0);
        const float q1 = fabsf(g1) - t1;
        if (q1 > 0.f) rr += copysignf(q1, g1);
        const int idx16 = (swzc(hb + r, o >> 1) << 1) | (o & 1);
        const float Fv = bf2f(t16[idx16]);  // residual in wavelet domain
        t16[idx16] = f2bf(rr + Fv);
      }
    }
  }
  __syncthreads();

  // ---- inverse S3: levels 8,7 ----
  if (tid < 32) {
    unsigned int g[4];
#pragma unroll
    for (int k = 0; k < 4; ++k) g[k] = t32[swzc(k << 6, tid)];
    float fa[4], fb[4];
#pragma unroll
    for (int k = 0; k < 4; ++k) {
      fa[k] = bf2f(g[k]);
      fb[k] = bf2f(g[k] >> 16);
    }
    const float ua0 = kNorm * (fa[0] + fa[2]), ua1 = kNorm * (fa[0] - fa[2]);
    const float ub0 = kNorm * (fb[0] + fb[2]), ub1 = kNorm * (fb[0] - fb[2]);
    t32[swzc(0, tid)] = pk2(kNorm * (ua0 + fa[1]), kNorm * (ub0 + fb[1]));
    t32[swzc(64, tid)] = pk2(kNorm * (ua0 - fa[1]), kNorm * (ub0 - fb[1]));
    t32[swzc(128, tid)] = pk2(kNorm * (ua1 + fa[3]), kNorm * (ub1 + fb[3]));
    t32[swzc(192, tid)] = pk2(kNorm * (ua1 - fa[3]), kNorm * (ub1 - fb[3]));
  }
  __syncthreads();

  // ---- inverse S2: levels 6,5,4 ----
  if (tid < 128) {
    const int cd = tid & 31;
    const int h0 = (tid >> 5) << 6;
    unsigned int g[8];
#pragma unroll
    for (int k = 0; k < 8; ++k) g[k] = t32[swzc(h0 + (k << 3), cd)];
    float fa[8], fb[8], oa[8], ob[8];
#pragma unroll
    for (int k = 0; k < 8; ++k) {
      fa[k] = bf2f(g[k]);
      fb[k] = bf2f(g[k] >> 16);
    }
    ilift3f(fa, oa);
    ilift3f(fb, ob);
#pragma unroll
    for (int k = 0; k < 8; ++k)
      t32[swzc(h0 + (k << 3), cd)] = pk2(oa[k], ob[k]);
  }
  __syncthreads();

  // ---- inverse S1: levels 3,2,1 in registers + global store ----
#pragma unroll
  for (int it = 0; it < 4; ++it) {
    const int h0 = (o8 << 3) + (it << 6);
    unsigned int g[8];
#pragma unroll
    for (int j = 0; j < 8; ++j) g[j] = t32[swzc(h0 + j, cdw)];
    float fa[8], fb[8], oa[8], ob[8];
#pragma unroll
    for (int j = 0; j < 8; ++j) {
      fa[j] = bf2f(g[j]);
      fb[j] = bf2f(g[j] >> 16);
    }
    ilift3f(fa, oa);
    ilift3f(fb, ob);
    ushort8 sA, sB;
#pragma unroll
    for (int j = 0; j < 8; ++j) {
      sA[j] = f2bf(oa[j]);
      sB[j] = f2bf(ob[j]);
    }
    *reinterpret_cast<ushort8*>(base + ((size_t)c0 << 16) + h0) = sA;
    *reinterpret_cast<ushort8*>(base + ((size_t)(c0 + 1) << 16) + h0) = sB;
  }
}

// ---------------- Kernel 3: inverse Haar along W (packed h-pairs) -> y ------
__global__ __launch_bounds__(256) void k_invW(const unsigned short* __restrict__ at,
                                              float* __restrict__ y) {
  __shared__ unsigned int t[16][260];  // [hd][w in-place] packed h-pairs
  const int blk = blockIdx.x;          // img*8 + htile
  const int img = blk >> 3;
  const int h0 = (blk & 7) << 5;
  const int tid = threadIdx.x;

  // ---- gather: pure dword copy (ws already bf16 h-pairs) ----
  const unsigned short* __restrict__ basep = at + ((size_t)img << 16) + h0;
#pragma unroll
  for (int k = 0; k < 4; ++k) {
    const int idx = (k << 8) + tid;
    const int wp = idx >> 2;
    const int hq = (idx & 3) << 2;
    const int wr = ip2ref(wp);
    const uint4v qv = *reinterpret_cast<const uint4v*>(
        basep + ((size_t)wr << 8) + (hq << 1));
    t[hq][wp] = qv[0];
    t[hq + 1][wp] = qv[1];
    t[hq + 2][wp] = qv[2];
    t[hq + 3][wp] = qv[3];
  }
  __syncthreads();

  // ---- inverse S3: levels 8,7 on {0,64,128,192} ----
  if (tid < 16) {
    const unsigned d0 = t[tid][0], d1 = t[tid][64];
    const unsigned d2 = t[tid][128], d3 = t[tid][192];
    const float e0 = bf2f(d0), e1 = bf2f(d1), e2 = bf2f(d2), e3 = bf2f(d3);
    const float p0 = bf2f(d0 >> 16), p1 = bf2f(d1 >> 16);
    const float p2 = bf2f(d2 >> 16), p3 = bf2f(d3 >> 16);
    const float ue0 = kNorm * (e0 + e2), ue1 = kNorm * (e0 - e2);
    const float uo0 = kNorm * (p0 + p2), uo1 = kNorm * (p0 - p2);
    t[tid][0] = pk2(kNorm * (ue0 + e1), kNorm * (uo0 + p1));
    t[tid][64] = pk2(kNorm * (ue0 - e1), kNorm * (uo0 - p1));
    t[tid][128] = pk2(kNorm * (ue1 + e3), kNorm * (uo1 + p3));
    t[tid][192] = pk2(kNorm * (ue1 - e3), kNorm * (uo1 - p3));
  }
  __syncthreads();

  // ---- inverse S2: levels 6,5,4 on stride-8 positions (staggered) ----
  if (tid < 64) {
    const int hd2 = tid & 15;
    const int q = tid >> 4;
    const int wq = q << 6;
    unsigned gd[8];
#pragma unroll
    for (int k0 = 0; k0 < 8; ++k0) {
      const int k = (k0 + (q << 1)) & 7;
      gd[k] = t[hd2][wq + (k << 3)];
    }
    float fe[8], fo[8], oe[8], oo[8];
#pragma unroll
    for (int k = 0; k < 8; ++k) {
      fe[k] = bf2f(gd[k]);
      fo[k] = bf2f(gd[k] >> 16);
    }
    ilift3f(fe, oe);
    ilift3f(fo, oo);
#pragma unroll
    for (int k0 = 0; k0 < 8; ++k0) {
      const int k = (k0 + (q << 1)) & 7;
      t[hd2][wq + (k << 3)] = pk2(oe[k], oo[k]);
    }
  }
  __syncthreads();

  // ---- inverse S1: levels 3,2,1 in registers, y store (rows 2hd, 2hd+1) ----
  const int g = tid & 7;
  const int hd = (tid >> 3) & 15;
  const int half = tid >> 7;
  float* __restrict__ yr0 =
      y + ((size_t)img << 16) + ((size_t)h0 << 8) + (hd << 9);
  float* __restrict__ yr1 = yr0 + 256;
#pragma unroll
  for (int it = 0; it < 2; ++it) {
    const int w0 = (g + (half << 3) + (it << 4)) << 3;
    const uint4v qa = *reinterpret_cast<const uint4v*>(&t[hd][w0]);
    const uint4v qb = *reinterpret_cast<const uint4v*>(&t[hd][w0 + 4]);
    float fe[8], fo[8], oe[8], oo[8];
#pragma unroll
    for (int j = 0; j < 4; ++j) {
      fe[j] = bf2f(qa[j]);
      fo[j] = bf2f(qa[j] >> 16);
      fe[4 + j] = bf2f(qb[j]);
      fo[4 + j] = bf2f(qb[j] >> 16);
    }
    ilift3f(fe, oe);
    ilift3f(fo, oo);
    float4 ya0 = {oe[0], oe[1], oe[2], oe[3]};
    float4 ya1 = {oe[4], oe[5], oe[6], oe[7]};
    float4 yb0 = {oo[0], oo[1], oo[2], oo[3]};
    float4 yb1 = {oo[4], oo[5], oo[6], oo[7]};
    *reinterpret_cast<float4*>(yr0 + w0) = ya0;
    *reinterpret_cast<float4*>(yr0 + w0 + 4) = ya1;
    *reinterpret_cast<float4*>(yr1 + w0) = yb0;
    *reinterpret_cast<float4*>(yr1 + w0 + 4) = yb1;
  }
}

}  // namespace

extern "C" void kernel_launch(void* const* d_in, const int* in_sizes, int n_in,
                              void* d_out, int out_size, void* d_ws, size_t ws_size,
                              hipStream_t stream) {
  (void)in_sizes; (void)n_in; (void)out_size; (void)ws_size;
  const float* x  = (const float*)d_in[0];
  const float* vv = (const float*)d_in[1];
  const float* cw = (const float*)d_in[2];
  const float* tt = (const float*)d_in[3];
  float* y = (float*)d_out;
  unsigned short* ws = (unsigned short*)d_ws;      // 128 MiB bf16 slab
  unsigned short* wb = ws + ((size_t)64 << 20);    // bf16 weights (16 KiB)
  unsigned int* vpk = (unsigned int*)(ws + ((size_t)64 << 20) + 16384);
  unsigned int* tpk = vpk + 65536;                 // 256 KiB each

  k_prep<<<256, 256, 0, stream>>>(cw, vv, tt, wb, vpk, tpk);
  k_fwdW<<<8192, 256, 0, stream>>>(x, ws);
  k_mid <<<4096, 256, 0, stream>>>(ws, wb, vpk, tpk);
  k_invW<<<8192, 256, 0, stream>>>(ws, y);
}

// Round 17
// 262.032 us; speedup vs baseline: 1.2353x; 1.0018x over previous
//
#include <hip/hip_runtime.h>
#include <hip/hip_bf16.h>

// Problem: B=16, C=64, H=256, W=256, P=2
// y = haar2d_inv( sum_p softthr( (haar2d(x)*v_p) @ w_p^T, tau_p ) ) + x
// Residual folded in wavelet domain: y = invHaar2d(acc + Haar2d(x)).
//
// ws: bf16 (b,c,wref,h) slab (128 MiB) + bf16 weights + packed/permuted v,tau.
//   k_prep : conv_w->bf16; v,tau -> bf16x2 packed, [w][h_inplace] layout
//   k_fwdW : x(f32) -> Hw(x), packed h-pair LDS tile, dword transposed store.
//   k_mid  : per (b,w) slab: staged Haar-H fwd -> MFMA mix (+F residual) ->
//            staged inverse -> store. NEW: weights staged to LDS (16 KiB,
//            XOR-swizzled) and ds_read_b128 per og -- removes the 64-reg
//            AGPR-parked Bf array that capped occupancy at 2 blocks/CU
//            (r13 spill / r14 hoist / r15 L1-serialization all confirmed
//            registers were the binding constraint). Now LDS-capped at
//            3 blocks/CU (50 KiB). Tripwires: WRITE_SIZE 131072 KB,
//            VGPR_Count not 64-clamped.
//   k_invW : dword gather -> staged inverse lifting -> y.

namespace {

constexpr float kNorm = 0.70710678118654752440f;

typedef __attribute__((ext_vector_type(8))) short short8;
typedef __attribute__((ext_vector_type(4))) float f32x4;
typedef __attribute__((ext_vector_type(8))) unsigned short ushort8;
typedef __attribute__((ext_vector_type(4))) unsigned int uint4v;

// in-place lifting position -> reference subband position (n=256, 8 levels)
__device__ __forceinline__ int ip2ref(int p) {
  if (p == 0) return 0;
  const int j = __builtin_ctz(p) + 1;
  return (256 >> j) + (p >> j);
}
// reference subband position -> in-place lifting position
__device__ __forceinline__ int ref2ip(int r) {
  if (r == 0) return 0;
  const int tb = 31 - __builtin_clz(r);
  const int j = 8 - tb;
  return ((r - (1 << tb)) << j) | (1 << (j - 1));
}

__device__ __forceinline__ unsigned short f2bf(float f) {  // f32->bf16 RN
  unsigned int u = __float_as_uint(f);
  u += 0x7FFFu + ((u >> 16) & 1u);
  return (unsigned short)(u >> 16);
}
__device__ __forceinline__ float bf2f(unsigned int u) {
  return __uint_as_float((u & 0xFFFFu) << 16);
}
__device__ __forceinline__ unsigned pk2(float lo, float hi) {
  return (unsigned)f2bf(lo) | ((unsigned)f2bf(hi) << 16);
}

// 3-level forward Haar lifting on 8 values (in-place position convention)
__device__ __forceinline__ void lift3f(const float f[8], float o[8]) {
  const float a0 = kNorm * (f[0] + f[1]), d10 = kNorm * (f[0] - f[1]);
  const float a1 = kNorm * (f[2] + f[3]), d11 = kNorm * (f[2] - f[3]);
  const float a2 = kNorm * (f[4] + f[5]), d12 = kNorm * (f[4] - f[5]);
  const float a3 = kNorm * (f[6] + f[7]), d13 = kNorm * (f[6] - f[7]);
  const float b0 = kNorm * (a0 + a1), d20 = kNorm * (a0 - a1);
  const float b1 = kNorm * (a2 + a3), d21 = kNorm * (a2 - a3);
  o[0] = kNorm * (b0 + b1);
  o[4] = kNorm * (b0 - b1);
  o[2] = d20; o[6] = d21;
  o[1] = d10; o[3] = d11; o[5] = d12; o[7] = d13;
}
// inverse of lift3f
__device__ __forceinline__ void ilift3f(const float f[8], float o[8]) {
  const float b0 = kNorm * (f[0] + f[4]), b1 = kNorm * (f[0] - f[4]);
  const float a0 = kNorm * (b0 + f[2]), a1 = kNorm * (b0 - f[2]);
  const float a2 = kNorm * (b1 + f[6]), a3 = kNorm * (b1 - f[6]);
  o[0] = kNorm * (a0 + f[1]); o[1] = kNorm * (a0 - f[1]);
  o[2] = kNorm * (a1 + f[3]); o[3] = kNorm * (a1 - f[3]);
  o[4] = kNorm * (a2 + f[5]); o[5] = kNorm * (a2 - f[5]);
  o[6] = kNorm * (a3 + f[7]); o[7] = kNorm * (a3 - f[7]);
}

// ---------------- Kernel 0: weights -> bf16; v,tau -> packed/permuted -------
__global__ __launch_bounds__(256) void k_prep(const float* __restrict__ cw,
                                              const float* __restrict__ vv,
                                              const float* __restrict__ tt,
                                              unsigned short* __restrict__ wb,
                                              unsigned int* __restrict__ vpk,
                                              unsigned int* __restrict__ tpk) {
  const int idx = blockIdx.x * 256 + threadIdx.x;  // 65536 = 256 w x 256 hp
  if (idx < 8192) wb[idx] = f2bf(cw[idx]);
  const int w = idx >> 8;
  const int hp = idx & 255;                 // in-place h position
  const int off = (ip2ref(hp) << 8) + w;    // reference coord
  vpk[idx] = pk2(vv[off], vv[65536 + off]);
  tpk[idx] = pk2(tt[off], tt[65536 + off]);
}

// ---------------- Kernel 1: forward Haar along W (packed h-pairs) -----------
__global__ __launch_bounds__(256) void k_fwdW(const float* __restrict__ x,
                                              unsigned short* __restrict__ xt) {
  __shared__ unsigned int t[16][260];  // [hd][w] packed (h=2hd lo, 2hd+1 hi)
  const int blk = blockIdx.x;          // img*8 + htile
  const int img = blk >> 3;            // b*64 + c
  const int h0 = (blk & 7) << 5;
  const int tid = threadIdx.x;

  const float* __restrict__ src = x + ((size_t)img << 16) + ((size_t)h0 << 8);
  const int g = tid & 7;
  const int hd = (tid >> 3) & 15;
  const int half = tid >> 7;

  // ---- S1: levels 1-3 in registers, rows 2hd & 2hd+1, b128 LDS writes ----
  const float* __restrict__ r0 = src + (hd << 9);
  const float* __restrict__ r1 = r0 + 256;
#pragma unroll
  for (int it = 0; it < 2; ++it) {
    const int w0 = (g + (half << 3) + (it << 4)) << 3;
    const float4 a0 = *reinterpret_cast<const float4*>(r0 + w0);
    const float4 a1 = *reinterpret_cast<const float4*>(r0 + w0 + 4);
    const float4 b0 = *reinterpret_cast<const float4*>(r1 + w0);
    const float4 b1 = *reinterpret_cast<const float4*>(r1 + w0 + 4);
    float fe[8] = {a0.x, a0.y, a0.z, a0.w, a1.x, a1.y, a1.z, a1.w};
    float fo[8] = {b0.x, b0.y, b0.z, b0.w, b1.x, b1.y, b1.z, b1.w};
    float oe[8], oo[8];
    lift3f(fe, oe);
    lift3f(fo, oo);
    uint4v q0 = {pk2(oe[0], oo[0]), pk2(oe[1], oo[1]),
                 pk2(oe[2], oo[2]), pk2(oe[3], oo[3])};
    uint4v q1 = {pk2(oe[4], oo[4]), pk2(oe[5], oo[5]),
                 pk2(oe[6], oo[6]), pk2(oe[7], oo[7])};
    *reinterpret_cast<uint4v*>(&t[hd][w0]) = q0;
    *reinterpret_cast<uint4v*>(&t[hd][w0 + 4]) = q1;
  }
  __syncthreads();

  // ---- S2: levels 4-6 on stride-8 positions (2q-staggered k order) ----
  if (tid < 64) {
    const int hd2 = tid & 15;
    const int q = tid >> 4;  // 0..3
    const int wq = q << 6;
    unsigned gd[8];
#pragma unroll
    for (int k0 = 0; k0 < 8; ++k0) {
      const int k = (k0 + (q << 1)) & 7;
      gd[k] = t[hd2][wq + (k << 3)];
    }
    float fe[8], fo[8], oe[8], oo[8];
#pragma unroll
    for (int k = 0; k < 8; ++k) {
      fe[k] = bf2f(gd[k]);
      fo[k] = bf2f(gd[k] >> 16);
    }
    lift3f(fe, oe);
    lift3f(fo, oo);
#pragma unroll
    for (int k0 = 0; k0 < 8; ++k0) {
      const int k = (k0 + (q << 1)) & 7;
      t[hd2][wq + (k << 3)] = pk2(oe[k], oo[k]);
    }
  }
  __syncthreads();

  // ---- S3: levels 7-8 on {0,64,128,192} ----
  if (tid < 16) {
    const unsigned d0 = t[tid][0], d1 = t[tid][64];
    const unsigned d2 = t[tid][128], d3 = t[tid][192];
    const float e0 = bf2f(d0), e1 = bf2f(d1), e2 = bf2f(d2), e3 = bf2f(d3);
    const float p0 = bf2f(d0 >> 16), p1 = bf2f(d1 >> 16);
    const float p2 = bf2f(d2 >> 16), p3 = bf2f(d3 >> 16);
    const float ae0 = kNorm * (e0 + e1), de0 = kNorm * (e0 - e1);
    const float ae1 = kNorm * (e2 + e3), de1 = kNorm * (e2 - e3);
    const float ao0 = kNorm * (p0 + p1), do0 = kNorm * (p0 - p1);
    const float ao1 = kNorm * (p2 + p3), do1 = kNorm * (p2 - p3);
    t[tid][0] = pk2(kNorm * (ae0 + ae1), kNorm * (ao0 + ao1));
    t[tid][64] = pk2(de0, do0);
    t[tid][128] = pk2(kNorm * (ae0 - ae1), kNorm * (ao0 - ao1));
    t[tid][192] = pk2(de1, do1);
  }
  __syncthreads();

  // ---- transposed+permuted store: pure dword copy (already bf16 pairs) ----
  unsigned short* __restrict__ dst = xt + ((size_t)img << 16) + h0;
#pragma unroll
  for (int k = 0; k < 4; ++k) {
    const int idx = (k << 8) + tid;
    const int wp = idx >> 2;          // in-place w
    const int hq = (idx & 3) << 2;    // dword base: 0,4,8,12 (h = 2hq..2hq+7)
    const int wr = ip2ref(wp);
    uint4v qv = {t[hq][wp], t[hq + 1][wp], t[hq + 2][wp], t[hq + 3][wp]};
    *reinterpret_cast<uint4v*>(dst + ((size_t)wr << 8) + (hq << 1)) = qv;
  }
}

// ---------------- Kernel 2: staged Haar-H + MFMA mix (h-major packed LDS) ---
// tile dword (h, cdw): dwidx = h*32 + ((cdw + 4*(h&7) + 8*((h>>3)&3)) & 31)
__device__ __forceinline__ int swzc(int h, int cdw) {
  return (h << 5) | ((cdw + ((h & 7) << 2) + (((h >> 3) & 3) << 3)) & 31);
}
// weight LDS dword index: row r' in [0,128) (p*64+o), dword d in [0,32)
// XOR swizzle keeps b128 alignment (mask is a multiple of 4) and makes the
// GEMM's 16-lane row-slice read 2-way (free).
__device__ __forceinline__ int swzw(int rp, int d) {
  return (rp << 5) | (d ^ ((rp & 7) << 2));
}

__global__ __launch_bounds__(256, 3) void k_mid(
    unsigned short* __restrict__ ws, const unsigned short* __restrict__ wb,
    const unsigned int* __restrict__ vpk, const unsigned int* __restrict__ tpk) {
  __shared__ unsigned int t32[8192];   // 32 KiB: [h=256][cdw=32] swizzled
  __shared__ unsigned int vt[512];     // v packed / tau packed
  __shared__ unsigned int wl[4096];    // 16 KiB: weights, [r'=128][d=32] swz
  unsigned short* t16 = reinterpret_cast<unsigned short*>(t32);

  const int blk = blockIdx.x;  // b*256 + w
  const int b = blk >> 8;
  const int w = blk & 255;
  const int tid = threadIdx.x;

  unsigned short* __restrict__ base = ws + ((size_t)b << 22) + ((size_t)w << 8);

  // stage v/tau (coalesced; already ip2ref-permuted by k_prep)
  vt[tid] = vpk[(w << 8) + tid];
  vt[256 + tid] = tpk[(w << 8) + tid];

  // ---- stage weights to LDS (one-time, 16 dwords/thread, coalesced) ----
  {
    const unsigned int* __restrict__ wb32 =
        reinterpret_cast<const unsigned int*>(wb);
#pragma unroll
    for (int k = 0; k < 16; ++k) {
      const int L = (tid << 4) + k;  // linear dword: r' = L>>5, d = L&31
      wl[swzw(L >> 5, L & 31)] = wb32[L];
    }
  }

  // ---- S1: global->reg, fwd levels 1-3 in registers, write tile ----
  const int cdw = tid >> 3;  // 0..31 (channel pair)
  const int c0 = cdw << 1;
  const int o8 = tid & 7;
#pragma unroll
  for (int it = 0; it < 4; ++it) {
    const int h0 = (o8 << 3) + (it << 6);
    const ushort8 rA =
        *reinterpret_cast<const ushort8*>(base + ((size_t)c0 << 16) + h0);
    const ushort8 rB =
        *reinterpret_cast<const ushort8*>(base + ((size_t)(c0 + 1) << 16) + h0);
    float fa[8], fb[8], oa[8], ob[8];
#pragma unroll
    for (int j = 0; j < 8; ++j) {
      fa[j] = bf2f(rA[j]);
      fb[j] = bf2f(rB[j]);
    }
    lift3f(fa, oa);
    lift3f(fb, ob);
#pragma unroll
    for (int j = 0; j < 8; ++j) t32[swzc(h0 + j, cdw)] = pk2(oa[j], ob[j]);
  }
  __syncthreads();

  // ---- S2: fwd levels 4-6 (8 values @ stride 8), 128 threads ----
  if (tid < 128) {
    const int cd = tid & 31;
    const int h0 = (tid >> 5) << 6;
    unsigned int g[8];
#pragma unroll
    for (int k = 0; k < 8; ++k) g[k] = t32[swzc(h0 + (k << 3), cd)];
    float fa[8], fb[8], oa[8], ob[8];
#pragma unroll
    for (int k = 0; k < 8; ++k) {
      fa[k] = bf2f(g[k]);
      fb[k] = bf2f(g[k] >> 16);
    }
    lift3f(fa, oa);
    lift3f(fb, ob);
#pragma unroll
    for (int k = 0; k < 8; ++k)
      t32[swzc(h0 + (k << 3), cd)] = pk2(oa[k], ob[k]);
  }
  __syncthreads();

  // ---- S3: fwd levels 7-8 (4 values @ stride 64), 32 threads ----
  if (tid < 32) {
    unsigned int g[4];
#pragma unroll
    for (int k = 0; k < 4; ++k) g[k] = t32[swzc(k << 6, tid)];
    float fa[4], fb[4];
#pragma unroll
    for (int k = 0; k < 4; ++k) {
      fa[k] = bf2f(g[k]);
      fb[k] = bf2f(g[k] >> 16);
    }
    const float aa0 = kNorm * (fa[0] + fa[1]), da0 = kNorm * (fa[0] - fa[1]);
    const float aa1 = kNorm * (fa[2] + fa[3]), da1 = kNorm * (fa[2] - fa[3]);
    const float ab0 = kNorm * (fb[0] + fb[1]), db0 = kNorm * (fb[0] - fb[1]);
    const float ab1 = kNorm * (fb[2] + fb[3]), db1 = kNorm * (fb[2] - fb[3]);
    t32[swzc(0, tid)] = pk2(kNorm * (aa0 + aa1), kNorm * (ab0 + ab1));
    t32[swzc(64, tid)] = pk2(da0, db0);
    t32[swzc(128, tid)] = pk2(kNorm * (aa0 - aa1), kNorm * (ab0 - ab1));
    t32[swzc(192, tid)] = pk2(da1, db1);
  }
  __syncthreads();

  // ---- GEMM + fused epilogue (acc + F residual), per-wave 64-row strip ----
  // B fragments come from LDS (wl) per og: 4x ds_read_b128, prefetchable
  // across the unrolled og loop. Live set ~<100 regs -> no AGPR parking.
  const int l15 = tid & 15;
  const int l4 = (tid & 63) >> 4;
  const int strip = (tid >> 6) << 6;
  const int dA = l4 << 2;  // dword base within half-row (f*16 + l4*4)
#pragma unroll 1
  for (int mt = 0; mt < 4; ++mt) {
    const int hh = strip + (mt << 4) + l15;
    const short8 a0 =
        *reinterpret_cast<const short8*>(&t32[swzc(hh, l4 << 2)]);
    const short8 a1 =
        *reinterpret_cast<const short8*>(&t32[swzc(hh, 16 + (l4 << 2))]);
    const int hb = strip + (mt << 4) + (l4 << 2);
    const uint4v vq = *reinterpret_cast<const uint4v*>(&vt[hb]);
    const uint4v tq = *reinterpret_cast<const uint4v*>(&vt[256 + hb]);
#pragma unroll
    for (int og = 0; og < 4; ++og) {
      const int o = (og << 4) + l15;
      const int rp0 = o;        // p=0 row'
      const int rp1 = 64 + o;   // p=1 row'
      const short8 b0 =
          *reinterpret_cast<const short8*>(&wl[swzw(rp0, dA)]);
      const short8 b1 =
          *reinterpret_cast<const short8*>(&wl[swzw(rp0, 16 + dA)]);
      const short8 c0v =
          *reinterpret_cast<const short8*>(&wl[swzw(rp1, dA)]);
      const short8 c1v =
          *reinterpret_cast<const short8*>(&wl[swzw(rp1, 16 + dA)]);
      f32x4 accL = {0.f, 0.f, 0.f, 0.f};
      f32x4 accH = {0.f, 0.f, 0.f, 0.f};
      accL = __builtin_amdgcn_mfma_f32_16x16x32_bf16(a0, b0, accL, 0, 0, 0);
      accH = __builtin_amdgcn_mfma_f32_16x16x32_bf16(a0, c0v, accH, 0, 0, 0);
      accL = __builtin_amdgcn_mfma_f32_16x16x32_bf16(a1, b1, accL, 0, 0, 0);
      accH = __builtin_amdgcn_mfma_f32_16x16x32_bf16(a1, c1v, accH, 0, 0, 0);
#pragma unroll
      for (int r = 0; r < 4; ++r) {
        const float v0 = bf2f(vq[r]), v1 = bf2f(vq[r] >> 16);
        const float t0 = bf2f(tq[r]), t1 = bf2f(tq[r] >> 16);
        const float g0 = accL[r] * v0;
        const float g1 = accH[r] * v1;
        float rr = 0.f;
        const float q0 = fabsf(g0) - t0;
        if (q0 > 0.f) rr += copysignf(q0, g0);
        const float q1 = fabsf(g1) - t1;
        if (q1 > 0.f) rr += copysignf(q1, g1);
        const int idx16 = (swzc(hb + r, o >> 1) << 1) | (o & 1);
        const float Fv = bf2f(t16[idx16]);  // residual in wavelet domain
        t16[idx16] = f2bf(rr + Fv);
      }
    }
  }
  __syncthreads();

  // ---- inverse S3: levels 8,7 ----
  if (tid < 32) {
    unsigned int g[4];
#pragma unroll
    for (int k = 0; k < 4; ++k) g[k] = t32[swzc(k << 6, tid)];
    float fa[4], fb[4];
#pragma unroll
    for (int k = 0; k < 4; ++k) {
      fa[k] = bf2f(g[k]);
      fb[k] = bf2f(g[k] >> 16);
    }
    const float ua0 = kNorm * (fa[0] + fa[2]), ua1 = kNorm * (fa[0] - fa[2]);
    const float ub0 = kNorm * (fb[0] + fb[2]), ub1 = kNorm * (fb[0] - fb[2]);
    t32[swzc(0, tid)] = pk2(kNorm * (ua0 + fa[1]), kNorm * (ub0 + fb[1]));
    t32[swzc(64, tid)] = pk2(kNorm * (ua0 - fa[1]), kNorm * (ub0 - fb[1]));
    t32[swzc(128, tid)] = pk2(kNorm * (ua1 + fa[3]), kNorm * (ub1 + fb[3]));
    t32[swzc(192, tid)] = pk2(kNorm * (ua1 - fa[3]), kNorm * (ub1 - fb[3]));
  }
  __syncthreads();

  // ---- inverse S2: levels 6,5,4 ----
  if (tid < 128) {
    const int cd = tid & 31;
    const int h0 = (tid >> 5) << 6;
    unsigned int g[8];
#pragma unroll
    for (int k = 0; k < 8; ++k) g[k] = t32[swzc(h0 + (k << 3), cd)];
    float fa[8], fb[8], oa[8], ob[8];
#pragma unroll
    for (int k = 0; k < 8; ++k) {
      fa[k] = bf2f(g[k]);
      fb[k] = bf2f(g[k] >> 16);
    }
    ilift3f(fa, oa);
    ilift3f(fb, ob);
#pragma unroll
    for (int k = 0; k < 8; ++k)
      t32[swzc(h0 + (k << 3), cd)] = pk2(oa[k], ob[k]);
  }
  __syncthreads();

  // ---- inverse S1: levels 3,2,1 in registers + global store ----
#pragma unroll
  for (int it = 0; it < 4; ++it) {
    const int h0 = (o8 << 3) + (it << 6);
    unsigned int g[8];
#pragma unroll
    for (int j = 0; j < 8; ++j) g[j] = t32[swzc(h0 + j, cdw)];
    float fa[8], fb[8], oa[8], ob[8];
#pragma unroll
    for (int j = 0; j < 8; ++j) {
      fa[j] = bf2f(g[j]);
      fb[j] = bf2f(g[j] >> 16);
    }
    ilift3f(fa, oa);
    ilift3f(fb, ob);
    ushort8 sA, sB;
#pragma unroll
    for (int j = 0; j < 8; ++j) {
      sA[j] = f2bf(oa[j]);
      sB[j] = f2bf(ob[j]);
    }
    *reinterpret_cast<ushort8*>(base + ((size_t)c0 << 16) + h0) = sA;
    *reinterpret_cast<ushort8*>(base + ((size_t)(c0 + 1) << 16) + h0) = sB;
  }
}

// ---------------- Kernel 3: inverse Haar along W (packed h-pairs) -> y ------
__global__ __launch_bounds__(256) void k_invW(const unsigned short* __restrict__ at,
                                              float* __restrict__ y) {
  __shared__ unsigned int t[16][260];  // [hd][w in-place] packed h-pairs
  const int blk = blockIdx.x;          // img*8 + htile
  const int img = blk >> 3;
  const int h0 = (blk & 7) << 5;
  const int tid = threadIdx.x;

  // ---- gather: pure dword copy (ws already bf16 h-pairs) ----
  const unsigned short* __restrict__ basep = at + ((size_t)img << 16) + h0;
#pragma unroll
  for (int k = 0; k < 4; ++k) {
    const int idx = (k << 8) + tid;
    const int wp = idx >> 2;
    const int hq = (idx & 3) << 2;
    const int wr = ip2ref(wp);
    const uint4v qv = *reinterpret_cast<const uint4v*>(
        basep + ((size_t)wr << 8) + (hq << 1));
    t[hq][wp] = qv[0];
    t[hq + 1][wp] = qv[1];
    t[hq + 2][wp] = qv[2];
    t[hq + 3][wp] = qv[3];
  }
  __syncthreads();

  // ---- inverse S3: levels 8,7 on {0,64,128,192} ----
  if (tid < 16) {
    const unsigned d0 = t[tid][0], d1 = t[tid][64];
    const unsigned d2 = t[tid][128], d3 = t[tid][192];
    const float e0 = bf2f(d0), e1 = bf2f(d1), e2 = bf2f(d2), e3 = bf2f(d3);
    const float p0 = bf2f(d0 >> 16), p1 = bf2f(d1 >> 16);
    const float p2 = bf2f(d2 >> 16), p3 = bf2f(d3 >> 16);
    const float ue0 = kNorm * (e0 + e2), ue1 = kNorm * (e0 - e2);
    const float uo0 = kNorm * (p0 + p2), uo1 = kNorm * (p0 - p2);
    t[tid][0] = pk2(kNorm * (ue0 + e1), kNorm * (uo0 + p1));
    t[tid][64] = pk2(kNorm * (ue0 - e1), kNorm * (uo0 - p1));
    t[tid][128] = pk2(kNorm * (ue1 + e3), kNorm * (uo1 + p3));
    t[tid][192] = pk2(kNorm * (ue1 - e3), kNorm * (uo1 - p3));
  }
  __syncthreads();

  // ---- inverse S2: levels 6,5,4 on stride-8 positions (staggered) ----
  if (tid < 64) {
    const int hd2 = tid & 15;
    const int q = tid >> 4;
    const int wq = q << 6;
    unsigned gd[8];
#pragma unroll
    for (int k0 = 0; k0 < 8; ++k0) {
      const int k = (k0 + (q << 1)) & 7;
      gd[k] = t[hd2][wq + (k << 3)];
    }
    float fe[8], fo[8], oe[8], oo[8];
#pragma unroll
    for (int k = 0; k < 8; ++k) {
      fe[k] = bf2f(gd[k]);
      fo[k] = bf2f(gd[k] >> 16);
    }
    ilift3f(fe, oe);
    ilift3f(fo, oo);
#pragma unroll
    for (int k0 = 0; k0 < 8; ++k0) {
      const int k = (k0 + (q << 1)) & 7;
      t[hd2][wq + (k << 3)] = pk2(oe[k], oo[k]);
    }
  }
  __syncthreads();

  // ---- inverse S1: levels 3,2,1 in registers, y store (rows 2hd, 2hd+1) ----
  const int g = tid & 7;
  const int hd = (tid >> 3) & 15;
  const int half = tid >> 7;
  float* __restrict__ yr0 =
      y + ((size_t)img << 16) + ((size_t)h0 << 8) + (hd << 9);
  float* __restrict__ yr1 = yr0 + 256;
#pragma unroll
  for (int it = 0; it < 2; ++it) {
    const int w0 = (g + (half << 3) + (it << 4)) << 3;
    const uint4v qa = *reinterpret_cast<const uint4v*>(&t[hd][w0]);
    const uint4v qb = *reinterpret_cast<const uint4v*>(&t[hd][w0 + 4]);
    float fe[8], fo[8], oe[8], oo[8];
#pragma unroll
    for (int j = 0; j < 4; ++j) {
      fe[j] = bf2f(qa[j]);
      fo[j] = bf2f(qa[j] >> 16);
      fe[4 + j] = bf2f(qb[j]);
      fo[4 + j] = bf2f(qb[j] >> 16);
    }
    ilift3f(fe, oe);
    ilift3f(fo, oo);
    float4 ya0 = {oe[0], oe[1], oe[2], oe[3]};
    float4 ya1 = {oe[4], oe[5], oe[6], oe[7]};
    float4 yb0 = {oo[0], oo[1], oo[2], oo[3]};
    float4 yb1 = {oo[4], oo[5], oo[6], oo[7]};
    *reinterpret_cast<float4*>(yr0 + w0) = ya0;
    *reinterpret_cast<float4*>(yr0 + w0 + 4) = ya1;
    *reinterpret_cast<float4*>(yr1 + w0) = yb0;
    *reinterpret_cast<float4*>(yr1 + w0 + 4) = yb1;
  }
}

}  // namespace

extern "C" void kernel_launch(void* const* d_in, const int* in_sizes, int n_in,
                              void* d_out, int out_size, void* d_ws, size_t ws_size,
                              hipStream_t stream) {
  (void)in_sizes; (void)n_in; (void)out_size; (void)ws_size;
  const float* x  = (const float*)d_in[0];
  const float* vv = (const float*)d_in[1];
  const float* cw = (const float*)d_in[2];
  const float* tt = (const float*)d_in[3];
  float* y = (float*)d_out;
  unsigned short* ws = (unsigned short*)d_ws;      // 128 MiB bf16 slab
  unsigned short* wb = ws + ((size_t)64 << 20);    // bf16 weights (16 KiB)
  unsigned int* vpk = (unsigned int*)(ws + ((size_t)64 << 20) + 16384);
  unsigned int* tpk = vpk + 65536;                 // 256 KiB each

  k_prep<<<256, 256, 0, stream>>>(cw, vv, tt, wb, vpk, tpk);
  k_fwdW<<<8192, 256, 0, stream>>>(x, ws);
  k_mid <<<4096, 256, 0, stream>>>(ws, wb, vpk, tpk);
  k_invW<<<8192, 256, 0, stream>>>(ws, y);
}